// Round 1
// baseline (1423.428 us; speedup 1.0000x reference)
//
#include <hip/hip_runtime.h>

#define N_NODES 50000
#define N_EDGES 800000
#define HID 128
#define NCLS 10
#define NG 64

// ---------------- CSR build ----------------

__global__ void count_edges_k(const int* __restrict__ dst, int* __restrict__ deg) {
    int i = blockIdx.x * blockDim.x + threadIdx.x;
    if (i < N_EDGES) atomicAdd(&deg[dst[i]], 1);
}

__global__ void count_batch_k(const int* __restrict__ batch, int* __restrict__ gcount) {
    int i = blockIdx.x * blockDim.x + threadIdx.x;
    if (i < N_NODES) atomicAdd(&gcount[batch[i]], 1);
}

__global__ __launch_bounds__(1024) void scan_k(const int* __restrict__ deg,
                                               int* __restrict__ rowptr,
                                               int* __restrict__ cursor) {
    __shared__ int part[1024];
    int tid = threadIdx.x;
    const int chunk = (N_NODES + 1023) / 1024;  // 49
    int s0 = tid * chunk;
    int s1 = min(s0 + chunk, N_NODES);
    int s = 0;
    for (int i = s0; i < s1; i++) s += deg[i];
    part[tid] = s;
    __syncthreads();
    for (int off = 1; off < 1024; off <<= 1) {
        int v = (tid >= off) ? part[tid - off] : 0;
        __syncthreads();
        part[tid] += v;
        __syncthreads();
    }
    int excl = (tid == 0) ? 0 : part[tid - 1];
    for (int i = s0; i < s1; i++) {
        rowptr[i] = excl;
        cursor[i] = excl;
        excl += deg[i];
    }
    if (tid == 1023) rowptr[N_NODES] = excl;
}

__global__ void gscan_k(const int* __restrict__ gcount, int* __restrict__ gstart,
                        float* __restrict__ countsf) {
    int g = threadIdx.x;
    if (g == 0) {
        int acc = 0;
        for (int i = 0; i < NG; i++) { gstart[i] = acc; acc += gcount[i]; }
    }
    if (g < NG) countsf[g] = fmaxf((float)gcount[g], 1.0f);
}

__global__ void scatter_k(const int* __restrict__ src, const int* __restrict__ dst,
                          int* __restrict__ cursor, int* __restrict__ csr) {
    int i = blockIdx.x * blockDim.x + threadIdx.x;
    if (i < N_EDGES) {
        int d = dst[i];
        int pos = atomicAdd(&cursor[d], 1);
        csr[pos] = src[i];
    }
}

// ---------------- Aggregation: h[n] = (2+eps)*x[n] + sum_{e: dst=n} x[src[e]] ----------------
// One wave per node. F=128: lane handles feature lane and lane+64.

__global__ __launch_bounds__(256) void agg128_k(const float* __restrict__ X,
                                                const int* __restrict__ rowptr,
                                                const int* __restrict__ csr,
                                                const float* __restrict__ eps,
                                                float* __restrict__ H) {
    int wid = (blockIdx.x * 256 + threadIdx.x) >> 6;
    int lane = threadIdx.x & 63;
    if (wid >= N_NODES) return;
    float scale = 2.0f + eps[0];
    const float* xr = X + (size_t)wid * 128;
    float a0 = scale * xr[lane];
    float a1 = scale * xr[lane + 64];
    int e0 = rowptr[wid], e1 = rowptr[wid + 1];
    for (int e = e0; e < e1; e++) {
        const float* xs = X + (size_t)csr[e] * 128;
        a0 += xs[lane];
        a1 += xs[lane + 64];
    }
    float* hr = H + (size_t)wid * 128;
    hr[lane] = a0;
    hr[lane + 64] = a1;
}

__global__ __launch_bounds__(256) void agg64_k(const float* __restrict__ X,
                                               const int* __restrict__ rowptr,
                                               const int* __restrict__ csr,
                                               const float* __restrict__ eps,
                                               float* __restrict__ H) {
    int wid = (blockIdx.x * 256 + threadIdx.x) >> 6;
    int lane = threadIdx.x & 63;
    if (wid >= N_NODES) return;
    float scale = 2.0f + eps[0];
    float a0 = scale * X[(size_t)wid * 64 + lane];
    int e0 = rowptr[wid], e1 = rowptr[wid + 1];
    for (int e = e0; e < e1; e++) {
        a0 += X[(size_t)csr[e] * 64 + lane];
    }
    H[(size_t)wid * 64 + lane] = a0;
}

// ---------------- GEMM: out[M x 128] = act(H1@W1 (+ H2@W2) + bias) ----------------
// Block: 256 threads -> 16 rows x 128 cols. act: 0 none, 1 lrelu(0.2), 2 relu.

__global__ __launch_bounds__(256) void gemm_k(const float* __restrict__ H1,
                                              const float* __restrict__ W1, int K1,
                                              const float* __restrict__ H2,
                                              const float* __restrict__ W2, int K2,
                                              const float* __restrict__ bias,
                                              float* __restrict__ out, int act) {
    __shared__ float Ws[32 * 128];   // [k][col]
    __shared__ float HsT[32 * 16];   // [k][row]
    int tid = threadIdx.x;
    int c = tid & 63;       // cols 2c, 2c+1
    int rh = tid >> 6;      // rows rh*4 .. rh*4+3 (uniform per wave -> LDS broadcast)
    int row0 = blockIdx.x * 16;
    float acc[4][2];
#pragma unroll
    for (int j = 0; j < 4; j++) { acc[j][0] = 0.f; acc[j][1] = 0.f; }

    const float* H = H1;
    const float* W = W1;
    int K = K1;
    for (int pass = 0; pass < 2; ++pass) {
        if (pass) {
            if (H2 == nullptr) break;
            H = H2; W = W2; K = K2;
        }
        for (int k0 = 0; k0 < K; k0 += 32) {
#pragma unroll
            for (int i = 0; i < 16; i++)
                Ws[i * 256 + tid] = W[(size_t)k0 * 128 + i * 256 + tid];
#pragma unroll
            for (int i = 0; i < 2; i++) {
                int idx = i * 256 + tid;
                int k = idx & 31, r = idx >> 5;
                HsT[k * 16 + r] = H[(size_t)(row0 + r) * K + k0 + k];
            }
            __syncthreads();
#pragma unroll
            for (int k = 0; k < 32; k++) {
                float2 w = *(const float2*)&Ws[k * 128 + 2 * c];
                float4 h4 = *(const float4*)&HsT[k * 16 + rh * 4];
                float hv[4] = {h4.x, h4.y, h4.z, h4.w};
#pragma unroll
                for (int j = 0; j < 4; j++) {
                    acc[j][0] = fmaf(hv[j], w.x, acc[j][0]);
                    acc[j][1] = fmaf(hv[j], w.y, acc[j][1]);
                }
            }
            __syncthreads();
        }
    }
    float bx = bias[2 * c], by = bias[2 * c + 1];
#pragma unroll
    for (int j = 0; j < 4; j++) {
        int row = row0 + rh * 4 + j;
        float vx = acc[j][0] + bx;
        float vy = acc[j][1] + by;
        if (act == 1) {
            vx = vx > 0.f ? vx : 0.2f * vx;
            vy = vy > 0.f ? vy : 0.2f * vy;
        } else if (act == 2) {
            vx = fmaxf(vx, 0.f);
            vy = fmaxf(vy, 0.f);
        }
        float2 v = {vx, vy};
        *(float2*)&out[(size_t)row * 128 + 2 * c] = v;
    }
}

// ---------------- head GEMM N=10: ln = T@Wp2 + bp2 ----------------

__global__ __launch_bounds__(256) void gemm10_k(const float* __restrict__ T,
                                                const float* __restrict__ Wp2,
                                                const float* __restrict__ bp2,
                                                float* __restrict__ ln) {
    __shared__ float Ws[128 * NCLS];
    int tid = threadIdx.x;
    for (int i = tid; i < 128 * NCLS; i += 256) Ws[i] = Wp2[i];
    __syncthreads();
    int n = blockIdx.x * 256 + tid;
    if (n >= N_NODES) return;
    const float* tr = T + (size_t)n * 128;
    float acc[NCLS];
#pragma unroll
    for (int cc = 0; cc < NCLS; cc++) acc[cc] = bp2[cc];
    for (int k = 0; k < 128; k++) {
        float t = tr[k];
#pragma unroll
        for (int cc = 0; cc < NCLS; cc++) acc[cc] = fmaf(t, Ws[k * NCLS + cc], acc[cc]);
    }
#pragma unroll
    for (int cc = 0; cc < NCLS; cc++) ln[(size_t)n * NCLS + cc] = acc[cc];
}

// ---------------- pooling ----------------

__global__ void pool128_k(const float* __restrict__ X, const int* __restrict__ gstart,
                          const int* __restrict__ gcount, const float* __restrict__ countsf,
                          float* __restrict__ out) {
    int g = blockIdx.x;
    int f = threadIdx.x;  // 128 threads
    int s = gstart[g], cnt = gcount[g];
    float acc = 0.f;
    for (int i = 0; i < cnt; i++) acc += X[(size_t)(s + i) * 128 + f];
    out[g * 128 + f] = acc / countsf[g];
}

__global__ void pool10_k(const float* __restrict__ LN, const int* __restrict__ gstart,
                         const int* __restrict__ gcount, const float* __restrict__ countsf,
                         float* __restrict__ out) {
    int g = blockIdx.x;
    int f = threadIdx.x;  // 64 threads, f<10 active
    if (f >= NCLS) return;
    int s = gstart[g], cnt = gcount[g];
    float acc = 0.f;
    for (int i = 0; i < cnt; i++) acc += LN[(size_t)(s + i) * NCLS + f];
    out[NG * 128 + g * NCLS + f] = acc / countsf[g];
}

// ---------------- launch ----------------

extern "C" void kernel_launch(void* const* d_in, const int* in_sizes, int n_in,
                              void* d_out, int out_size, void* d_ws, size_t ws_size,
                              hipStream_t stream) {
    const float* exp_f = (const float*)d_in[0];
    const float* cnv_f = (const float*)d_in[1];
    const int*   ei    = (const int*)d_in[2];
    const int*   batch = (const int*)d_in[3];
    const float* eps1e = (const float*)d_in[4];
    const float* W1e   = (const float*)d_in[5];
    const float* b1e   = (const float*)d_in[6];
    const float* eps2e = (const float*)d_in[7];
    const float* W2e   = (const float*)d_in[8];
    const float* b2e   = (const float*)d_in[9];
    const float* eps1c = (const float*)d_in[10];
    const float* W1c   = (const float*)d_in[11];
    const float* b1c   = (const float*)d_in[12];
    const float* eps2c = (const float*)d_in[13];
    const float* W2c   = (const float*)d_in[14];
    const float* b2c   = (const float*)d_in[15];
    const float* Wm    = (const float*)d_in[16];
    const float* bm    = (const float*)d_in[17];
    const float* Wp1   = (const float*)d_in[18];
    const float* bp1   = (const float*)d_in[19];
    const float* Wp2   = (const float*)d_in[20];
    const float* bp2   = (const float*)d_in[21];
    float* out = (float*)d_out;

    char* ws = (char*)d_ws;
    size_t off = 0;
    auto alloc = [&](size_t bytes) -> void* {
        void* p = ws + off;
        off = (off + bytes + 255) & ~(size_t)255;
        return p;
    };
    int* deg     = (int*)alloc((size_t)N_NODES * 4);
    int* rowptr  = (int*)alloc((size_t)(N_NODES + 1) * 4);
    int* cursor  = (int*)alloc((size_t)N_NODES * 4);
    int* csr     = (int*)alloc((size_t)N_EDGES * 4);
    int* gcount  = (int*)alloc(NG * 4);
    int* gstart  = (int*)alloc(NG * 4);
    float* countsf = (float*)alloc(NG * 4);
    float* A = (float*)alloc((size_t)N_NODES * 128 * 4);
    float* B = (float*)alloc((size_t)N_NODES * 128 * 4);
    float* C = (float*)alloc((size_t)N_NODES * 128 * 4);
    float* D = (float*)alloc((size_t)N_NODES * 128 * 4);

    const int* src = ei;
    const int* dst = ei + N_EDGES;

    hipMemsetAsync(deg, 0, (size_t)N_NODES * 4, stream);
    hipMemsetAsync(gcount, 0, NG * 4, stream);

    count_edges_k<<<(N_EDGES + 255) / 256, 256, 0, stream>>>(dst, deg);
    count_batch_k<<<(N_NODES + 255) / 256, 256, 0, stream>>>(batch, gcount);
    scan_k<<<1, 1024, 0, stream>>>(deg, rowptr, cursor);
    gscan_k<<<1, 64, 0, stream>>>(gcount, gstart, countsf);
    scatter_k<<<(N_EDGES + 255) / 256, 256, 0, stream>>>(src, dst, cursor, csr);

    const int AGG_GRID = (N_NODES * 64 + 255) / 256;
    const int GEMM_GRID = N_NODES / 16;  // 3125, exact

    // exp branch
    agg128_k<<<AGG_GRID, 256, 0, stream>>>(exp_f, rowptr, csr, eps1e, A);
    gemm_k<<<GEMM_GRID, 256, 0, stream>>>(A, W1e, 128, nullptr, nullptr, 0, b1e, B, 1);
    agg128_k<<<AGG_GRID, 256, 0, stream>>>(B, rowptr, csr, eps2e, A);
    gemm_k<<<GEMM_GRID, 256, 0, stream>>>(A, W2e, 128, nullptr, nullptr, 0, b2e, B, 1);
    // cnv branch
    agg64_k<<<AGG_GRID, 256, 0, stream>>>(cnv_f, rowptr, csr, eps1c, A);
    gemm_k<<<GEMM_GRID, 256, 0, stream>>>(A, W1c, 64, nullptr, nullptr, 0, b1c, C, 1);
    agg128_k<<<AGG_GRID, 256, 0, stream>>>(C, rowptr, csr, eps2c, A);
    gemm_k<<<GEMM_GRID, 256, 0, stream>>>(A, W2c, 128, nullptr, nullptr, 0, b2c, C, 1);
    // mix: D = lrelu(B@Wm_top + C@Wm_bot + bm)
    gemm_k<<<GEMM_GRID, 256, 0, stream>>>(B, Wm, 128, C, Wm + 128 * 128, 128, bm, D, 1);
    // graph_repr
    pool128_k<<<NG, 128, 0, stream>>>(D, gstart, gcount, countsf, out);
    // head: A = relu(D@Wp1+bp1); ln(C) = A@Wp2+bp2; pool
    gemm_k<<<GEMM_GRID, 256, 0, stream>>>(D, Wp1, 128, nullptr, nullptr, 0, bp1, A, 2);
    gemm10_k<<<(N_NODES + 255) / 256, 256, 0, stream>>>(A, Wp2, bp2, C);
    pool10_k<<<NG, 64, 0, stream>>>(C, gstart, gcount, countsf, out);
}

// Round 2
// 1173.610 us; speedup vs baseline: 1.2129x; 1.2129x over previous
//
#include <hip/hip_runtime.h>

#define N_NODES 50000
#define N_EDGES 800000
#define HID 128
#define NCLS 10
#define NG 64

// ---------------- CSR build ----------------

__global__ void count_edges_k(const int* __restrict__ dst, int* __restrict__ deg) {
    int i = blockIdx.x * blockDim.x + threadIdx.x;
    if (i < N_EDGES) atomicAdd(&deg[dst[i]], 1);
}

// batch is sorted: find graph boundaries without atomics.
// gstart has NG+1 entries.
__global__ void gbounds_k(const int* __restrict__ batch, int* __restrict__ gstart) {
    int i = blockIdx.x * blockDim.x + threadIdx.x;
    if (i >= N_NODES) return;
    int b = batch[i];
    int prev = (i == 0) ? -1 : batch[i - 1];
    for (int g = prev + 1; g <= b; g++) gstart[g] = i;
    if (i == N_NODES - 1) {
        for (int g = b + 1; g <= NG; g++) gstart[g] = N_NODES;
    }
}

__global__ void gfin_k(const int* __restrict__ gstart, int* __restrict__ gcount,
                       float* __restrict__ countsf) {
    int g = threadIdx.x;
    if (g < NG) {
        int c = gstart[g + 1] - gstart[g];
        gcount[g] = c;
        countsf[g] = fmaxf((float)c, 1.0f);
    }
}

__global__ __launch_bounds__(1024) void scan_k(const int* __restrict__ deg,
                                               int* __restrict__ rowptr,
                                               int* __restrict__ cursor) {
    __shared__ int part[1024];
    int tid = threadIdx.x;
    const int chunk = (N_NODES + 1023) / 1024;  // 49
    int s0 = tid * chunk;
    int s1 = min(s0 + chunk, N_NODES);
    int s = 0;
    for (int i = s0; i < s1; i++) s += deg[i];
    part[tid] = s;
    __syncthreads();
    for (int off = 1; off < 1024; off <<= 1) {
        int v = (tid >= off) ? part[tid - off] : 0;
        __syncthreads();
        part[tid] += v;
        __syncthreads();
    }
    int excl = (tid == 0) ? 0 : part[tid - 1];
    for (int i = s0; i < s1; i++) {
        rowptr[i] = excl;
        cursor[i] = excl;
        excl += deg[i];
    }
    if (tid == 1023) rowptr[N_NODES] = excl;
}

__global__ void scatter_k(const int* __restrict__ src, const int* __restrict__ dst,
                          int* __restrict__ cursor, int* __restrict__ csr) {
    int i = blockIdx.x * blockDim.x + threadIdx.x;
    if (i < N_EDGES) {
        int d = dst[i];
        int pos = atomicAdd(&cursor[d], 1);
        csr[pos] = src[i];
    }
}

// ---------------- Aggregation: h[n] = (2+eps)*x[n] + sum_{e: dst=n} x[src[e]] ----------------
// One wave per node. F=128: lane handles feature lane and lane+64.

__global__ __launch_bounds__(256) void agg128_k(const float* __restrict__ X,
                                                const int* __restrict__ rowptr,
                                                const int* __restrict__ csr,
                                                const float* __restrict__ eps,
                                                float* __restrict__ H) {
    int wid = (blockIdx.x * 256 + threadIdx.x) >> 6;
    int lane = threadIdx.x & 63;
    if (wid >= N_NODES) return;
    float scale = 2.0f + eps[0];
    const float* xr = X + (size_t)wid * 128;
    float a0 = scale * xr[lane];
    float a1 = scale * xr[lane + 64];
    int e0 = rowptr[wid], e1 = rowptr[wid + 1];
    for (int e = e0; e < e1; e++) {
        const float* xs = X + (size_t)csr[e] * 128;
        a0 += xs[lane];
        a1 += xs[lane + 64];
    }
    float* hr = H + (size_t)wid * 128;
    hr[lane] = a0;
    hr[lane + 64] = a1;
}

__global__ __launch_bounds__(256) void agg64_k(const float* __restrict__ X,
                                               const int* __restrict__ rowptr,
                                               const int* __restrict__ csr,
                                               const float* __restrict__ eps,
                                               float* __restrict__ H) {
    int wid = (blockIdx.x * 256 + threadIdx.x) >> 6;
    int lane = threadIdx.x & 63;
    if (wid >= N_NODES) return;
    float scale = 2.0f + eps[0];
    float a0 = scale * X[(size_t)wid * 64 + lane];
    int e0 = rowptr[wid], e1 = rowptr[wid + 1];
    for (int e = e0; e < e1; e++) {
        a0 += X[(size_t)csr[e] * 64 + lane];
    }
    H[(size_t)wid * 64 + lane] = a0;
}

// ---------------- GEMM: out[M x 128] = act(H1@W1 (+ H2@W2) + bias) ----------------
// Block: 256 threads -> 16 rows x 128 cols. act: 0 none, 1 lrelu(0.2), 2 relu.

__global__ __launch_bounds__(256) void gemm_k(const float* __restrict__ H1,
                                              const float* __restrict__ W1, int K1,
                                              const float* __restrict__ H2,
                                              const float* __restrict__ W2, int K2,
                                              const float* __restrict__ bias,
                                              float* __restrict__ out, int act) {
    __shared__ float Ws[32 * 128];   // [k][col]
    __shared__ float HsT[32 * 16];   // [k][row]
    int tid = threadIdx.x;
    int c = tid & 63;       // cols 2c, 2c+1
    int rh = tid >> 6;      // rows rh*4 .. rh*4+3 (uniform per wave -> LDS broadcast)
    int row0 = blockIdx.x * 16;
    float acc[4][2];
#pragma unroll
    for (int j = 0; j < 4; j++) { acc[j][0] = 0.f; acc[j][1] = 0.f; }

    const float* H = H1;
    const float* W = W1;
    int K = K1;
    for (int pass = 0; pass < 2; ++pass) {
        if (pass) {
            if (H2 == nullptr) break;
            H = H2; W = W2; K = K2;
        }
        for (int k0 = 0; k0 < K; k0 += 32) {
#pragma unroll
            for (int i = 0; i < 16; i++)
                Ws[i * 256 + tid] = W[(size_t)k0 * 128 + i * 256 + tid];
#pragma unroll
            for (int i = 0; i < 2; i++) {
                int idx = i * 256 + tid;
                int k = idx & 31, r = idx >> 5;
                HsT[k * 16 + r] = H[(size_t)(row0 + r) * K + k0 + k];
            }
            __syncthreads();
#pragma unroll
            for (int k = 0; k < 32; k++) {
                float2 w = *(const float2*)&Ws[k * 128 + 2 * c];
                float4 h4 = *(const float4*)&HsT[k * 16 + rh * 4];
                float hv[4] = {h4.x, h4.y, h4.z, h4.w};
#pragma unroll
                for (int j = 0; j < 4; j++) {
                    acc[j][0] = fmaf(hv[j], w.x, acc[j][0]);
                    acc[j][1] = fmaf(hv[j], w.y, acc[j][1]);
                }
            }
            __syncthreads();
        }
    }
    float bx = bias[2 * c], by = bias[2 * c + 1];
#pragma unroll
    for (int j = 0; j < 4; j++) {
        int row = row0 + rh * 4 + j;
        float vx = acc[j][0] + bx;
        float vy = acc[j][1] + by;
        if (act == 1) {
            vx = vx > 0.f ? vx : 0.2f * vx;
            vy = vy > 0.f ? vy : 0.2f * vy;
        } else if (act == 2) {
            vx = fmaxf(vx, 0.f);
            vy = fmaxf(vy, 0.f);
        }
        float2 v = {vx, vy};
        *(float2*)&out[(size_t)row * 128 + 2 * c] = v;
    }
}

// ---------------- head GEMM N=10: ln = T@Wp2 + bp2 ----------------

__global__ __launch_bounds__(256) void gemm10_k(const float* __restrict__ T,
                                                const float* __restrict__ Wp2,
                                                const float* __restrict__ bp2,
                                                float* __restrict__ ln) {
    __shared__ float Ws[128 * NCLS];
    int tid = threadIdx.x;
    for (int i = tid; i < 128 * NCLS; i += 256) Ws[i] = Wp2[i];
    __syncthreads();
    int n = blockIdx.x * 256 + tid;
    if (n >= N_NODES) return;
    const float* tr = T + (size_t)n * 128;
    float acc[NCLS];
#pragma unroll
    for (int cc = 0; cc < NCLS; cc++) acc[cc] = bp2[cc];
    for (int k = 0; k < 128; k++) {
        float t = tr[k];
#pragma unroll
        for (int cc = 0; cc < NCLS; cc++) acc[cc] = fmaf(t, Ws[k * NCLS + cc], acc[cc]);
    }
#pragma unroll
    for (int cc = 0; cc < NCLS; cc++) ln[(size_t)n * NCLS + cc] = acc[cc];
}

// ---------------- pooling ----------------

__global__ void pool128_k(const float* __restrict__ X, const int* __restrict__ gstart,
                          const int* __restrict__ gcount, const float* __restrict__ countsf,
                          float* __restrict__ out) {
    int g = blockIdx.x;
    int f = threadIdx.x;  // 128 threads
    int s = gstart[g], cnt = gcount[g];
    float acc = 0.f;
    for (int i = 0; i < cnt; i++) acc += X[(size_t)(s + i) * 128 + f];
    out[g * 128 + f] = acc / countsf[g];
}

__global__ void pool10_k(const float* __restrict__ LN, const int* __restrict__ gstart,
                         const int* __restrict__ gcount, const float* __restrict__ countsf,
                         float* __restrict__ out) {
    int g = blockIdx.x;
    int f = threadIdx.x;  // 64 threads, f<10 active
    if (f >= NCLS) return;
    int s = gstart[g], cnt = gcount[g];
    float acc = 0.f;
    for (int i = 0; i < cnt; i++) acc += LN[(size_t)(s + i) * NCLS + f];
    out[NG * 128 + g * NCLS + f] = acc / countsf[g];
}

// ---------------- launch ----------------

extern "C" void kernel_launch(void* const* d_in, const int* in_sizes, int n_in,
                              void* d_out, int out_size, void* d_ws, size_t ws_size,
                              hipStream_t stream) {
    const float* exp_f = (const float*)d_in[0];
    const float* cnv_f = (const float*)d_in[1];
    const int*   ei    = (const int*)d_in[2];
    const int*   batch = (const int*)d_in[3];
    const float* eps1e = (const float*)d_in[4];
    const float* W1e   = (const float*)d_in[5];
    const float* b1e   = (const float*)d_in[6];
    const float* eps2e = (const float*)d_in[7];
    const float* W2e   = (const float*)d_in[8];
    const float* b2e   = (const float*)d_in[9];
    const float* eps1c = (const float*)d_in[10];
    const float* W1c   = (const float*)d_in[11];
    const float* b1c   = (const float*)d_in[12];
    const float* eps2c = (const float*)d_in[13];
    const float* W2c   = (const float*)d_in[14];
    const float* b2c   = (const float*)d_in[15];
    const float* Wm    = (const float*)d_in[16];
    const float* bm    = (const float*)d_in[17];
    const float* Wp1   = (const float*)d_in[18];
    const float* bp1   = (const float*)d_in[19];
    const float* Wp2   = (const float*)d_in[20];
    const float* bp2   = (const float*)d_in[21];
    float* out = (float*)d_out;

    char* ws = (char*)d_ws;
    size_t off = 0;
    auto alloc = [&](size_t bytes) -> void* {
        void* p = ws + off;
        off = (off + bytes + 255) & ~(size_t)255;
        return p;
    };
    int* deg     = (int*)alloc((size_t)N_NODES * 4);
    int* rowptr  = (int*)alloc((size_t)(N_NODES + 1) * 4);
    int* cursor  = (int*)alloc((size_t)N_NODES * 4);
    int* csr     = (int*)alloc((size_t)N_EDGES * 4);
    int* gstart  = (int*)alloc((NG + 1) * 4);
    int* gcount  = (int*)alloc(NG * 4);
    float* countsf = (float*)alloc(NG * 4);
    float* A = (float*)alloc((size_t)N_NODES * 128 * 4);
    float* B = (float*)alloc((size_t)N_NODES * 128 * 4);
    float* C = (float*)alloc((size_t)N_NODES * 128 * 4);
    float* D = (float*)alloc((size_t)N_NODES * 128 * 4);

    const int* src = ei;
    const int* dst = ei + N_EDGES;

    hipMemsetAsync(deg, 0, (size_t)N_NODES * 4, stream);

    count_edges_k<<<(N_EDGES + 255) / 256, 256, 0, stream>>>(dst, deg);
    gbounds_k<<<(N_NODES + 255) / 256, 256, 0, stream>>>(batch, gstart);
    scan_k<<<1, 1024, 0, stream>>>(deg, rowptr, cursor);
    gfin_k<<<1, 64, 0, stream>>>(gstart, gcount, countsf);
    scatter_k<<<(N_EDGES + 255) / 256, 256, 0, stream>>>(src, dst, cursor, csr);

    const int AGG_GRID = (N_NODES * 64 + 255) / 256;
    const int GEMM_GRID = N_NODES / 16;  // 3125, exact

    // exp branch
    agg128_k<<<AGG_GRID, 256, 0, stream>>>(exp_f, rowptr, csr, eps1e, A);
    gemm_k<<<GEMM_GRID, 256, 0, stream>>>(A, W1e, 128, nullptr, nullptr, 0, b1e, B, 1);
    agg128_k<<<AGG_GRID, 256, 0, stream>>>(B, rowptr, csr, eps2e, A);
    gemm_k<<<GEMM_GRID, 256, 0, stream>>>(A, W2e, 128, nullptr, nullptr, 0, b2e, B, 1);
    // cnv branch
    agg64_k<<<AGG_GRID, 256, 0, stream>>>(cnv_f, rowptr, csr, eps1c, A);
    gemm_k<<<GEMM_GRID, 256, 0, stream>>>(A, W1c, 64, nullptr, nullptr, 0, b1c, C, 1);
    agg128_k<<<AGG_GRID, 256, 0, stream>>>(C, rowptr, csr, eps2c, A);
    gemm_k<<<GEMM_GRID, 256, 0, stream>>>(A, W2c, 128, nullptr, nullptr, 0, b2c, C, 1);
    // mix: D = lrelu(B@Wm_top + C@Wm_bot + bm)
    gemm_k<<<GEMM_GRID, 256, 0, stream>>>(B, Wm, 128, C, Wm + 128 * 128, 128, bm, D, 1);
    // graph_repr
    pool128_k<<<NG, 128, 0, stream>>>(D, gstart, gcount, countsf, out);
    // head: A = relu(D@Wp1+bp1); ln(C) = A@Wp2+bp2; pool
    gemm_k<<<GEMM_GRID, 256, 0, stream>>>(D, Wp1, 128, nullptr, nullptr, 0, bp1, A, 2);
    gemm10_k<<<(N_NODES + 255) / 256, 256, 0, stream>>>(A, Wp2, bp2, C);
    pool10_k<<<NG, 64, 0, stream>>>(C, gstart, gcount, countsf, out);
}

// Round 3
// 942.165 us; speedup vs baseline: 1.5108x; 1.2457x over previous
//
#include <hip/hip_runtime.h>

#define N_NODES 50000
#define N_EDGES 800000
#define HID 128
#define NCLS 10
#define NG 64
#define PCHUNK 128

// ---------------- CSR build ----------------

__global__ void count_edges_k(const int* __restrict__ dst, int* __restrict__ deg) {
    int i = blockIdx.x * blockDim.x + threadIdx.x;
    if (i < N_EDGES) atomicAdd(&deg[dst[i]], 1);
}

// batch is sorted: find graph boundaries without atomics. gstart has NG+1 entries.
__global__ void gbounds_k(const int* __restrict__ batch, int* __restrict__ gstart) {
    int i = blockIdx.x * blockDim.x + threadIdx.x;
    if (i >= N_NODES) return;
    int b = batch[i];
    int prev = (i == 0) ? -1 : batch[i - 1];
    for (int g = prev + 1; g <= b; g++) gstart[g] = i;
    if (i == N_NODES - 1) {
        for (int g = b + 1; g <= NG; g++) gstart[g] = N_NODES;
    }
}

__global__ void gfin_k(const int* __restrict__ gstart, float* __restrict__ invcnt) {
    int g = threadIdx.x;
    if (g < NG) {
        int c = gstart[g + 1] - gstart[g];
        invcnt[g] = (c > 0) ? 1.0f / (float)c : 0.0f;
    }
}

__global__ __launch_bounds__(1024) void scan_k(const int* __restrict__ deg,
                                               int* __restrict__ rowptr,
                                               int* __restrict__ cursor) {
    __shared__ int part[1024];
    int tid = threadIdx.x;
    const int chunk = (N_NODES + 1023) / 1024;  // 49
    int s0 = tid * chunk;
    int s1 = min(s0 + chunk, N_NODES);
    int s = 0;
    for (int i = s0; i < s1; i++) s += deg[i];
    part[tid] = s;
    __syncthreads();
    for (int off = 1; off < 1024; off <<= 1) {
        int v = (tid >= off) ? part[tid - off] : 0;
        __syncthreads();
        part[tid] += v;
        __syncthreads();
    }
    int excl = (tid == 0) ? 0 : part[tid - 1];
    for (int i = s0; i < s1; i++) {
        rowptr[i] = excl;
        cursor[i] = excl;
        excl += deg[i];
    }
    if (tid == 1023) rowptr[N_NODES] = excl;
}

__global__ void scatter_k(const int* __restrict__ src, const int* __restrict__ dst,
                          int* __restrict__ cursor, int* __restrict__ csr) {
    int i = blockIdx.x * blockDim.x + threadIdx.x;
    if (i < N_EDGES) {
        int d = dst[i];
        int pos = atomicAdd(&cursor[d], 1);
        csr[pos] = src[i];
    }
}

// ---------------- Aggregation: h[n] = (2+eps)*x[n] + sum_{e: dst=n} x[src[e]] ----------------

__global__ __launch_bounds__(256) void agg128_k(const float* __restrict__ X,
                                                const int* __restrict__ rowptr,
                                                const int* __restrict__ csr,
                                                const float* __restrict__ eps,
                                                float* __restrict__ H) {
    int wid = (blockIdx.x * 256 + threadIdx.x) >> 6;
    int lane = threadIdx.x & 63;
    if (wid >= N_NODES) return;
    float scale = 2.0f + eps[0];
    const float* xr = X + (size_t)wid * 128;
    float a0 = scale * xr[lane];
    float a1 = scale * xr[lane + 64];
    int e0 = rowptr[wid], e1 = rowptr[wid + 1];
    for (int e = e0; e < e1; e++) {
        const float* xs = X + (size_t)csr[e] * 128;
        a0 += xs[lane];
        a1 += xs[lane + 64];
    }
    float* hr = H + (size_t)wid * 128;
    hr[lane] = a0;
    hr[lane + 64] = a1;
}

__global__ __launch_bounds__(256) void agg64_k(const float* __restrict__ X,
                                               const int* __restrict__ rowptr,
                                               const int* __restrict__ csr,
                                               const float* __restrict__ eps,
                                               float* __restrict__ H) {
    int wid = (blockIdx.x * 256 + threadIdx.x) >> 6;
    int lane = threadIdx.x & 63;
    if (wid >= N_NODES) return;
    float scale = 2.0f + eps[0];
    float a0 = scale * X[(size_t)wid * 64 + lane];
    int e0 = rowptr[wid], e1 = rowptr[wid + 1];
    for (int e = e0; e < e1; e++) {
        a0 += X[(size_t)csr[e] * 64 + lane];
    }
    H[(size_t)wid * 64 + lane] = a0;
}

// ---------------- GEMM: out[M x 128] = act(H1@W1 (+ H2@W2) + bias) ----------------

__global__ __launch_bounds__(256) void gemm_k(const float* __restrict__ H1,
                                              const float* __restrict__ W1, int K1,
                                              const float* __restrict__ H2,
                                              const float* __restrict__ W2, int K2,
                                              const float* __restrict__ bias,
                                              float* __restrict__ out, int act) {
    __shared__ float Ws[32 * 128];   // [k][col]
    __shared__ float HsT[32 * 16];   // [k][row]
    int tid = threadIdx.x;
    int c = tid & 63;       // cols 2c, 2c+1
    int rh = tid >> 6;      // rows rh*4 .. rh*4+3
    int row0 = blockIdx.x * 16;
    float acc[4][2];
#pragma unroll
    for (int j = 0; j < 4; j++) { acc[j][0] = 0.f; acc[j][1] = 0.f; }

    const float* H = H1;
    const float* W = W1;
    int K = K1;
    for (int pass = 0; pass < 2; ++pass) {
        if (pass) {
            if (H2 == nullptr) break;
            H = H2; W = W2; K = K2;
        }
        for (int k0 = 0; k0 < K; k0 += 32) {
#pragma unroll
            for (int i = 0; i < 16; i++)
                Ws[i * 256 + tid] = W[(size_t)k0 * 128 + i * 256 + tid];
#pragma unroll
            for (int i = 0; i < 2; i++) {
                int idx = i * 256 + tid;
                int k = idx & 31, r = idx >> 5;
                HsT[k * 16 + r] = H[(size_t)(row0 + r) * K + k0 + k];
            }
            __syncthreads();
#pragma unroll
            for (int k = 0; k < 32; k++) {
                float2 w = *(const float2*)&Ws[k * 128 + 2 * c];
                float4 h4 = *(const float4*)&HsT[k * 16 + rh * 4];
                float hv[4] = {h4.x, h4.y, h4.z, h4.w};
#pragma unroll
                for (int j = 0; j < 4; j++) {
                    acc[j][0] = fmaf(hv[j], w.x, acc[j][0]);
                    acc[j][1] = fmaf(hv[j], w.y, acc[j][1]);
                }
            }
            __syncthreads();
        }
    }
    float bx = bias[2 * c], by = bias[2 * c + 1];
#pragma unroll
    for (int j = 0; j < 4; j++) {
        int row = row0 + rh * 4 + j;
        float vx = acc[j][0] + bx;
        float vy = acc[j][1] + by;
        if (act == 1) {
            vx = vx > 0.f ? vx : 0.2f * vx;
            vy = vy > 0.f ? vy : 0.2f * vy;
        } else if (act == 2) {
            vx = fmaxf(vx, 0.f);
            vy = fmaxf(vy, 0.f);
        }
        float2 v = {vx, vy};
        *(float2*)&out[(size_t)row * 128 + 2 * c] = v;
    }
}

// ---------------- fused partial pooling over D and T ----------------
// Block = 128 threads (feature f), owns PCHUNK consecutive nodes. batch sorted;
// accumulate run, flush on graph change via atomicAdd (few per address).

__global__ __launch_bounds__(128) void pool2_partial_k(const float* __restrict__ D,
                                                       const float* __restrict__ T,
                                                       const int* __restrict__ batch,
                                                       float* __restrict__ sumD,
                                                       float* __restrict__ sumT) {
    int f = threadIdx.x;
    int i0 = blockIdx.x * PCHUNK;
    int i1 = min(i0 + PCHUNK, N_NODES);
    float ad = 0.f, at = 0.f;
    int g = batch[i0];
    for (int i = i0; i < i1; i++) {
        int bg = batch[i];
        if (bg != g) {
            atomicAdd(&sumD[g * 128 + f], ad);
            atomicAdd(&sumT[g * 128 + f], at);
            ad = 0.f; at = 0.f; g = bg;
        }
        ad += D[(size_t)i * 128 + f];
        at += T[(size_t)i * 128 + f];
    }
    atomicAdd(&sumD[g * 128 + f], ad);
    atomicAdd(&sumT[g * 128 + f], at);
}

// ---------------- finalize: out[0:8192] = sumD/cnt; out[8192:] = (sumT/cnt)@Wp2 + bp2 ----------------

__global__ __launch_bounds__(128) void finalize_k(const float* __restrict__ sumD,
                                                  const float* __restrict__ sumT,
                                                  const float* __restrict__ invcnt,
                                                  const float* __restrict__ Wp2,
                                                  const float* __restrict__ bp2,
                                                  float* __restrict__ out) {
    __shared__ float tr[128];
    int g = blockIdx.x;
    int f = threadIdx.x;
    float ic = invcnt[g];
    out[g * 128 + f] = sumD[g * 128 + f] * ic;
    tr[f] = sumT[g * 128 + f] * ic;
    __syncthreads();
    if (f < NCLS) {
        float acc = (ic > 0.f) ? bp2[f] : 0.f;
        for (int k = 0; k < 128; k++) acc = fmaf(tr[k], Wp2[k * NCLS + f], acc);
        out[NG * 128 + g * NCLS + f] = acc;
    }
}

// ---------------- launch ----------------

extern "C" void kernel_launch(void* const* d_in, const int* in_sizes, int n_in,
                              void* d_out, int out_size, void* d_ws, size_t ws_size,
                              hipStream_t stream) {
    const float* exp_f = (const float*)d_in[0];
    const float* cnv_f = (const float*)d_in[1];
    const int*   ei    = (const int*)d_in[2];
    const int*   batch = (const int*)d_in[3];
    const float* eps1e = (const float*)d_in[4];
    const float* W1e   = (const float*)d_in[5];
    const float* b1e   = (const float*)d_in[6];
    const float* eps2e = (const float*)d_in[7];
    const float* W2e   = (const float*)d_in[8];
    const float* b2e   = (const float*)d_in[9];
    const float* eps1c = (const float*)d_in[10];
    const float* W1c   = (const float*)d_in[11];
    const float* b1c   = (const float*)d_in[12];
    const float* eps2c = (const float*)d_in[13];
    const float* W2c   = (const float*)d_in[14];
    const float* b2c   = (const float*)d_in[15];
    const float* Wm    = (const float*)d_in[16];
    const float* bm    = (const float*)d_in[17];
    const float* Wp1   = (const float*)d_in[18];
    const float* bp1   = (const float*)d_in[19];
    const float* Wp2   = (const float*)d_in[20];
    const float* bp2   = (const float*)d_in[21];
    float* out = (float*)d_out;

    char* ws = (char*)d_ws;
    size_t off = 0;
    auto alloc = [&](size_t bytes) -> void* {
        void* p = ws + off;
        off = (off + bytes + 255) & ~(size_t)255;
        return p;
    };
    int* deg     = (int*)alloc((size_t)N_NODES * 4);
    int* rowptr  = (int*)alloc((size_t)(N_NODES + 1) * 4);
    int* cursor  = (int*)alloc((size_t)N_NODES * 4);
    int* csr     = (int*)alloc((size_t)N_EDGES * 4);
    int* gstart  = (int*)alloc((NG + 1) * 4);
    float* invcnt = (float*)alloc(NG * 4);
    float* sumD  = (float*)alloc((size_t)NG * 128 * 4);
    float* sumT  = (float*)alloc((size_t)NG * 128 * 4);
    float* A = (float*)alloc((size_t)N_NODES * 128 * 4);
    float* B = (float*)alloc((size_t)N_NODES * 128 * 4);
    float* C = (float*)alloc((size_t)N_NODES * 128 * 4);
    float* D = (float*)alloc((size_t)N_NODES * 128 * 4);

    const int* src = ei;
    const int* dst = ei + N_EDGES;

    hipMemsetAsync(deg, 0, (size_t)N_NODES * 4, stream);
    hipMemsetAsync(sumD, 0, (size_t)NG * 128 * 4 * 2, stream);  // sumD+sumT contiguous

    count_edges_k<<<(N_EDGES + 255) / 256, 256, 0, stream>>>(dst, deg);
    gbounds_k<<<(N_NODES + 255) / 256, 256, 0, stream>>>(batch, gstart);
    scan_k<<<1, 1024, 0, stream>>>(deg, rowptr, cursor);
    gfin_k<<<1, 64, 0, stream>>>(gstart, invcnt);
    scatter_k<<<(N_EDGES + 255) / 256, 256, 0, stream>>>(src, dst, cursor, csr);

    const int AGG_GRID = (N_NODES * 64 + 255) / 256;
    const int GEMM_GRID = N_NODES / 16;  // 3125, exact

    // exp branch
    agg128_k<<<AGG_GRID, 256, 0, stream>>>(exp_f, rowptr, csr, eps1e, A);
    gemm_k<<<GEMM_GRID, 256, 0, stream>>>(A, W1e, 128, nullptr, nullptr, 0, b1e, B, 1);
    agg128_k<<<AGG_GRID, 256, 0, stream>>>(B, rowptr, csr, eps2e, A);
    gemm_k<<<GEMM_GRID, 256, 0, stream>>>(A, W2e, 128, nullptr, nullptr, 0, b2e, B, 1);
    // cnv branch
    agg64_k<<<AGG_GRID, 256, 0, stream>>>(cnv_f, rowptr, csr, eps1c, A);
    gemm_k<<<GEMM_GRID, 256, 0, stream>>>(A, W1c, 64, nullptr, nullptr, 0, b1c, C, 1);
    agg128_k<<<AGG_GRID, 256, 0, stream>>>(C, rowptr, csr, eps2c, A);
    gemm_k<<<GEMM_GRID, 256, 0, stream>>>(A, W2c, 128, nullptr, nullptr, 0, b2c, C, 1);
    // mix: D = lrelu(B@Wm_top + C@Wm_bot + bm)
    gemm_k<<<GEMM_GRID, 256, 0, stream>>>(B, Wm, 128, C, Wm + 128 * 128, 128, bm, D, 1);
    // head pre-pool: A(T) = relu(D@Wp1+bp1)
    gemm_k<<<GEMM_GRID, 256, 0, stream>>>(D, Wp1, 128, nullptr, nullptr, 0, bp1, A, 2);
    // fused pooling of D and T, then finalize (logits head applied post-pool)
    pool2_partial_k<<<(N_NODES + PCHUNK - 1) / PCHUNK, 128, 0, stream>>>(D, A, batch, sumD, sumT);
    finalize_k<<<NG, 128, 0, stream>>>(sumD, sumT, invcnt, Wp2, bp2, out);
}

// Round 4
// 828.606 us; speedup vs baseline: 1.7179x; 1.1370x over previous
//
#include <hip/hip_runtime.h>

#define N_NODES 50000
#define N_EDGES 800000
#define HID 128
#define NCLS 10
#define NG 64
#define PCHUNK 128
#define NB_SCAN ((N_NODES + 255) / 256)   // 196

// ---------------- CSR build ----------------

__global__ void count_edges_k(const int* __restrict__ dst, int* __restrict__ deg) {
    int i = blockIdx.x * blockDim.x + threadIdx.x;
    if (i < N_EDGES) atomicAdd(&deg[dst[i]], 1);
}

// batch is sorted: find graph boundaries without atomics. gstart has NG+1 entries.
__global__ void gbounds_k(const int* __restrict__ batch, int* __restrict__ gstart) {
    int i = blockIdx.x * blockDim.x + threadIdx.x;
    if (i >= N_NODES) return;
    int b = batch[i];
    int prev = (i == 0) ? -1 : batch[i - 1];
    for (int g = prev + 1; g <= b; g++) gstart[g] = i;
    if (i == N_NODES - 1) {
        for (int g = b + 1; g <= NG; g++) gstart[g] = N_NODES;
    }
}

__global__ void gfin_k(const int* __restrict__ gstart, float* __restrict__ invcnt) {
    int g = threadIdx.x;
    if (g < NG) {
        int c = gstart[g + 1] - gstart[g];
        invcnt[g] = (c > 0) ? 1.0f / (float)c : 0.0f;
    }
}

// ---- multi-block exclusive scan of deg -> rowptr/cursor ----

__device__ __forceinline__ int block_excl_scan_256(int v, int tid, int* total_out) {
    // inclusive wave scan via shfl, then 4-wave combine in LDS
    int lane = tid & 63, w = tid >> 6;
    int x = v;
#pragma unroll
    for (int off = 1; off < 64; off <<= 1) {
        int y = __shfl_up(x, off, 64);
        if (lane >= off) x += y;
    }
    __shared__ int wsum[4];
    if (lane == 63) wsum[w] = x;
    __syncthreads();
    int add = 0;
#pragma unroll
    for (int i = 0; i < 4; i++) add += (i < w) ? wsum[i] : 0;
    int total = wsum[0] + wsum[1] + wsum[2] + wsum[3];
    if (total_out) *total_out = total;
    return x - v + add;  // exclusive
}

__global__ __launch_bounds__(256) void scan_partial_k(const int* __restrict__ deg,
                                                      int* __restrict__ rowptr,
                                                      int* __restrict__ blocksum) {
    int tid = threadIdx.x;
    int gid = blockIdx.x * 256 + tid;
    int v = (gid < N_NODES) ? deg[gid] : 0;
    int total;
    int excl = block_excl_scan_256(v, tid, &total);
    if (gid < N_NODES) rowptr[gid] = excl;
    if (tid == 0) blocksum[blockIdx.x] = total;
}

__global__ __launch_bounds__(256) void scan_root_k(const int* __restrict__ blocksum,
                                                   int* __restrict__ blockoff) {
    int tid = threadIdx.x;
    int v = (tid < NB_SCAN) ? blocksum[tid] : 0;
    int excl = block_excl_scan_256(v, tid, nullptr);
    if (tid < NB_SCAN) blockoff[tid] = excl;
}

__global__ __launch_bounds__(256) void scan_add_k(int* __restrict__ rowptr,
                                                  int* __restrict__ cursor,
                                                  const int* __restrict__ blockoff) {
    int gid = blockIdx.x * 256 + threadIdx.x;
    if (gid < N_NODES) {
        int r = rowptr[gid] + blockoff[blockIdx.x];
        rowptr[gid] = r;
        cursor[gid] = r;
    }
    if (gid == 0) rowptr[N_NODES] = N_EDGES;  // degrees sum to E exactly
}

__global__ void scatter_k(const int* __restrict__ src, const int* __restrict__ dst,
                          int* __restrict__ cursor, int* __restrict__ csr) {
    int i = blockIdx.x * blockDim.x + threadIdx.x;
    if (i < N_EDGES) {
        int d = dst[i];
        int pos = atomicAdd(&cursor[d], 1);
        csr[pos] = src[i];
    }
}

// ---------------- Aggregation: h[n] = (2+eps)*x[n] + sum_{e: dst=n} x[src[e]] ----------------

__global__ __launch_bounds__(256) void agg128_k(const float* __restrict__ X,
                                                const int* __restrict__ rowptr,
                                                const int* __restrict__ csr,
                                                const float* __restrict__ eps,
                                                float* __restrict__ H) {
    int wid = (blockIdx.x * 256 + threadIdx.x) >> 6;
    int lane = threadIdx.x & 63;
    if (wid >= N_NODES) return;
    float scale = 2.0f + eps[0];
    const float* xr = X + (size_t)wid * 128;
    float a0 = scale * xr[lane];
    float a1 = scale * xr[lane + 64];
    int e0 = rowptr[wid], e1 = rowptr[wid + 1];
    for (int e = e0; e < e1; e++) {
        const float* xs = X + (size_t)csr[e] * 128;
        a0 += xs[lane];
        a1 += xs[lane + 64];
    }
    float* hr = H + (size_t)wid * 128;
    hr[lane] = a0;
    hr[lane + 64] = a1;
}

__global__ __launch_bounds__(256) void agg64_k(const float* __restrict__ X,
                                               const int* __restrict__ rowptr,
                                               const int* __restrict__ csr,
                                               const float* __restrict__ eps,
                                               float* __restrict__ H) {
    int wid = (blockIdx.x * 256 + threadIdx.x) >> 6;
    int lane = threadIdx.x & 63;
    if (wid >= N_NODES) return;
    float scale = 2.0f + eps[0];
    float a0 = scale * X[(size_t)wid * 64 + lane];
    int e0 = rowptr[wid], e1 = rowptr[wid + 1];
    for (int e = e0; e < e1; e++) {
        a0 += X[(size_t)csr[e] * 64 + lane];
    }
    H[(size_t)wid * 64 + lane] = a0;
}

// ---------------- GEMM: out[M x 128] = act(H1@W1 (+ H2@W2) + bias) ----------------

__global__ __launch_bounds__(256) void gemm_k(const float* __restrict__ H1,
                                              const float* __restrict__ W1, int K1,
                                              const float* __restrict__ H2,
                                              const float* __restrict__ W2, int K2,
                                              const float* __restrict__ bias,
                                              float* __restrict__ out, int act) {
    __shared__ float Ws[32 * 128];   // [k][col]
    __shared__ float HsT[32 * 16];   // [k][row]
    int tid = threadIdx.x;
    int c = tid & 63;       // cols 2c, 2c+1
    int rh = tid >> 6;      // rows rh*4 .. rh*4+3
    int row0 = blockIdx.x * 16;
    float acc[4][2];
#pragma unroll
    for (int j = 0; j < 4; j++) { acc[j][0] = 0.f; acc[j][1] = 0.f; }

    const float* H = H1;
    const float* W = W1;
    int K = K1;
    for (int pass = 0; pass < 2; ++pass) {
        if (pass) {
            if (H2 == nullptr) break;
            H = H2; W = W2; K = K2;
        }
        for (int k0 = 0; k0 < K; k0 += 32) {
#pragma unroll
            for (int i = 0; i < 16; i++)
                Ws[i * 256 + tid] = W[(size_t)k0 * 128 + i * 256 + tid];
#pragma unroll
            for (int i = 0; i < 2; i++) {
                int idx = i * 256 + tid;
                int k = idx & 31, r = idx >> 5;
                HsT[k * 16 + r] = H[(size_t)(row0 + r) * K + k0 + k];
            }
            __syncthreads();
#pragma unroll
            for (int k = 0; k < 32; k++) {
                float2 w = *(const float2*)&Ws[k * 128 + 2 * c];
                float4 h4 = *(const float4*)&HsT[k * 16 + rh * 4];
                float hv[4] = {h4.x, h4.y, h4.z, h4.w};
#pragma unroll
                for (int j = 0; j < 4; j++) {
                    acc[j][0] = fmaf(hv[j], w.x, acc[j][0]);
                    acc[j][1] = fmaf(hv[j], w.y, acc[j][1]);
                }
            }
            __syncthreads();
        }
    }
    float bx = bias[2 * c], by = bias[2 * c + 1];
#pragma unroll
    for (int j = 0; j < 4; j++) {
        int row = row0 + rh * 4 + j;
        float vx = acc[j][0] + bx;
        float vy = acc[j][1] + by;
        if (act == 1) {
            vx = vx > 0.f ? vx : 0.2f * vx;
            vy = vy > 0.f ? vy : 0.2f * vy;
        } else if (act == 2) {
            vx = fmaxf(vx, 0.f);
            vy = fmaxf(vy, 0.f);
        }
        float2 v = {vx, vy};
        *(float2*)&out[(size_t)row * 128 + 2 * c] = v;
    }
}

// ---------------- fused partial pooling over D and T ----------------

__global__ __launch_bounds__(128) void pool2_partial_k(const float* __restrict__ D,
                                                       const float* __restrict__ T,
                                                       const int* __restrict__ batch,
                                                       float* __restrict__ sumD,
                                                       float* __restrict__ sumT) {
    int f = threadIdx.x;
    int i0 = blockIdx.x * PCHUNK;
    int i1 = min(i0 + PCHUNK, N_NODES);
    float ad = 0.f, at = 0.f;
    int g = batch[i0];
    for (int i = i0; i < i1; i++) {
        int bg = batch[i];
        if (bg != g) {
            atomicAdd(&sumD[g * 128 + f], ad);
            atomicAdd(&sumT[g * 128 + f], at);
            ad = 0.f; at = 0.f; g = bg;
        }
        ad += D[(size_t)i * 128 + f];
        at += T[(size_t)i * 128 + f];
    }
    atomicAdd(&sumD[g * 128 + f], ad);
    atomicAdd(&sumT[g * 128 + f], at);
}

// ---------------- finalize ----------------

__global__ __launch_bounds__(128) void finalize_k(const float* __restrict__ sumD,
                                                  const float* __restrict__ sumT,
                                                  const float* __restrict__ invcnt,
                                                  const float* __restrict__ Wp2,
                                                  const float* __restrict__ bp2,
                                                  float* __restrict__ out) {
    __shared__ float tr[128];
    int g = blockIdx.x;
    int f = threadIdx.x;
    float ic = invcnt[g];
    out[g * 128 + f] = sumD[g * 128 + f] * ic;
    tr[f] = sumT[g * 128 + f] * ic;
    __syncthreads();
    if (f < NCLS) {
        float acc = (ic > 0.f) ? bp2[f] : 0.f;
        for (int k = 0; k < 128; k++) acc = fmaf(tr[k], Wp2[k * NCLS + f], acc);
        out[NG * 128 + g * NCLS + f] = acc;
    }
}

// ---------------- launch ----------------

extern "C" void kernel_launch(void* const* d_in, const int* in_sizes, int n_in,
                              void* d_out, int out_size, void* d_ws, size_t ws_size,
                              hipStream_t stream) {
    const float* exp_f = (const float*)d_in[0];
    const float* cnv_f = (const float*)d_in[1];
    const int*   ei    = (const int*)d_in[2];
    const int*   batch = (const int*)d_in[3];
    const float* eps1e = (const float*)d_in[4];
    const float* W1e   = (const float*)d_in[5];
    const float* b1e   = (const float*)d_in[6];
    const float* eps2e = (const float*)d_in[7];
    const float* W2e   = (const float*)d_in[8];
    const float* b2e   = (const float*)d_in[9];
    const float* eps1c = (const float*)d_in[10];
    const float* W1c   = (const float*)d_in[11];
    const float* b1c   = (const float*)d_in[12];
    const float* eps2c = (const float*)d_in[13];
    const float* W2c   = (const float*)d_in[14];
    const float* b2c   = (const float*)d_in[15];
    const float* Wm    = (const float*)d_in[16];
    const float* bm    = (const float*)d_in[17];
    const float* Wp1   = (const float*)d_in[18];
    const float* bp1   = (const float*)d_in[19];
    const float* Wp2   = (const float*)d_in[20];
    const float* bp2   = (const float*)d_in[21];
    float* out = (float*)d_out;

    char* ws = (char*)d_ws;
    size_t off = 0;
    auto alloc = [&](size_t bytes) -> void* {
        void* p = ws + off;
        off = (off + bytes + 255) & ~(size_t)255;
        return p;
    };
    int* deg      = (int*)alloc((size_t)N_NODES * 4);
    int* rowptr   = (int*)alloc((size_t)(N_NODES + 1) * 4);
    int* cursor   = (int*)alloc((size_t)N_NODES * 4);
    int* csr      = (int*)alloc((size_t)N_EDGES * 4);
    int* gstart   = (int*)alloc((NG + 1) * 4);
    float* invcnt = (float*)alloc(NG * 4);
    int* blocksum = (int*)alloc(NB_SCAN * 4);
    int* blockoff = (int*)alloc(NB_SCAN * 4);
    float* sumD   = (float*)alloc((size_t)NG * 128 * 4);
    float* sumT   = (float*)alloc((size_t)NG * 128 * 4);
    float* A = (float*)alloc((size_t)N_NODES * 128 * 4);
    float* B = (float*)alloc((size_t)N_NODES * 128 * 4);
    float* C = (float*)alloc((size_t)N_NODES * 128 * 4);
    float* D = (float*)alloc((size_t)N_NODES * 128 * 4);

    const int* src = ei;
    const int* dst = ei + N_EDGES;

    hipMemsetAsync(deg, 0, (size_t)N_NODES * 4, stream);
    hipMemsetAsync(sumD, 0, (size_t)NG * 128 * 4 * 2, stream);  // sumD+sumT contiguous

    count_edges_k<<<(N_EDGES + 255) / 256, 256, 0, stream>>>(dst, deg);
    gbounds_k<<<(N_NODES + 255) / 256, 256, 0, stream>>>(batch, gstart);
    scan_partial_k<<<NB_SCAN, 256, 0, stream>>>(deg, rowptr, blocksum);
    scan_root_k<<<1, 256, 0, stream>>>(blocksum, blockoff);
    scan_add_k<<<NB_SCAN, 256, 0, stream>>>(rowptr, cursor, blockoff);
    gfin_k<<<1, 64, 0, stream>>>(gstart, invcnt);
    scatter_k<<<(N_EDGES + 255) / 256, 256, 0, stream>>>(src, dst, cursor, csr);

    const int AGG_GRID = (N_NODES * 64 + 255) / 256;
    const int GEMM_GRID = N_NODES / 16;  // 3125, exact

    // exp branch
    agg128_k<<<AGG_GRID, 256, 0, stream>>>(exp_f, rowptr, csr, eps1e, A);
    gemm_k<<<GEMM_GRID, 256, 0, stream>>>(A, W1e, 128, nullptr, nullptr, 0, b1e, B, 1);
    agg128_k<<<AGG_GRID, 256, 0, stream>>>(B, rowptr, csr, eps2e, A);
    gemm_k<<<GEMM_GRID, 256, 0, stream>>>(A, W2e, 128, nullptr, nullptr, 0, b2e, B, 1);
    // cnv branch
    agg64_k<<<AGG_GRID, 256, 0, stream>>>(cnv_f, rowptr, csr, eps1c, A);
    gemm_k<<<GEMM_GRID, 256, 0, stream>>>(A, W1c, 64, nullptr, nullptr, 0, b1c, C, 1);
    agg128_k<<<AGG_GRID, 256, 0, stream>>>(C, rowptr, csr, eps2c, A);
    gemm_k<<<GEMM_GRID, 256, 0, stream>>>(A, W2c, 128, nullptr, nullptr, 0, b2c, C, 1);
    // mix: D = lrelu(B@Wm_top + C@Wm_bot + bm)
    gemm_k<<<GEMM_GRID, 256, 0, stream>>>(B, Wm, 128, C, Wm + 128 * 128, 128, bm, D, 1);
    // head pre-pool: A(T) = relu(D@Wp1+bp1)
    gemm_k<<<GEMM_GRID, 256, 0, stream>>>(D, Wp1, 128, nullptr, nullptr, 0, bp1, A, 2);
    // fused pooling of D and T, then finalize (logits head applied post-pool)
    pool2_partial_k<<<(N_NODES + PCHUNK - 1) / PCHUNK, 128, 0, stream>>>(D, A, batch, sumD, sumT);
    finalize_k<<<NG, 128, 0, stream>>>(sumD, sumT, invcnt, Wp2, bp2, out);
}

// Round 5
// 694.422 us; speedup vs baseline: 2.0498x; 1.1932x over previous
//
#include <hip/hip_runtime.h>

#define N_NODES 50000
#define N_PAD   50016          // padded rows so OOB tile loads stay in-buffer
#define N_EDGES 800000
#define HID 128
#define NCLS 10
#define NG 64
#define PCHUNK 128
#define NB_SCAN ((N_NODES + 255) / 256)   // 196

typedef unsigned int uint32;
typedef unsigned short ushort16;
typedef __attribute__((ext_vector_type(8))) short bf16x8;
typedef __attribute__((ext_vector_type(4))) float f32x4;

// ---- bf16 helpers ----
__device__ __forceinline__ unsigned short f2bf(float f) {
    uint32 u = __float_as_uint(f);
    uint32 r = u + 0x7fffu + ((u >> 16) & 1u);   // RNE
    return (unsigned short)(r >> 16);
}
__device__ __forceinline__ float bflo(uint32 v) { return __uint_as_float(v << 16); }
__device__ __forceinline__ float bfhi(uint32 v) { return __uint_as_float(v & 0xffff0000u); }
__device__ __forceinline__ uint32 packbf(float a, float b) {
    return (uint32)f2bf(a) | ((uint32)f2bf(b) << 16);
}

// ---------------- CSR build ----------------

__global__ void count_edges_k(const int* __restrict__ dst, int* __restrict__ deg) {
    int i = blockIdx.x * blockDim.x + threadIdx.x;
    if (i < N_EDGES) atomicAdd(&deg[dst[i]], 1);
}

__global__ void gbounds_k(const int* __restrict__ batch, int* __restrict__ gstart) {
    int i = blockIdx.x * blockDim.x + threadIdx.x;
    if (i >= N_NODES) return;
    int b = batch[i];
    int prev = (i == 0) ? -1 : batch[i - 1];
    for (int g = prev + 1; g <= b; g++) gstart[g] = i;
    if (i == N_NODES - 1) {
        for (int g = b + 1; g <= NG; g++) gstart[g] = N_NODES;
    }
}

__global__ void gfin_k(const int* __restrict__ gstart, float* __restrict__ invcnt) {
    int g = threadIdx.x;
    if (g < NG) {
        int c = gstart[g + 1] - gstart[g];
        invcnt[g] = (c > 0) ? 1.0f / (float)c : 0.0f;
    }
}

__device__ __forceinline__ int block_excl_scan_256(int v, int tid, int* total_out) {
    int lane = tid & 63, w = tid >> 6;
    int x = v;
#pragma unroll
    for (int off = 1; off < 64; off <<= 1) {
        int y = __shfl_up(x, off, 64);
        if (lane >= off) x += y;
    }
    __shared__ int wsum[4];
    if (lane == 63) wsum[w] = x;
    __syncthreads();
    int add = 0;
#pragma unroll
    for (int i = 0; i < 4; i++) add += (i < w) ? wsum[i] : 0;
    int total = wsum[0] + wsum[1] + wsum[2] + wsum[3];
    if (total_out) *total_out = total;
    return x - v + add;
}

__global__ __launch_bounds__(256) void scan_partial_k(const int* __restrict__ deg,
                                                      int* __restrict__ rowptr,
                                                      int* __restrict__ blocksum) {
    int tid = threadIdx.x;
    int gid = blockIdx.x * 256 + tid;
    int v = (gid < N_NODES) ? deg[gid] : 0;
    int total;
    int excl = block_excl_scan_256(v, tid, &total);
    if (gid < N_NODES) rowptr[gid] = excl;
    if (tid == 0) blocksum[blockIdx.x] = total;
}

__global__ __launch_bounds__(256) void scan_root_k(const int* __restrict__ blocksum,
                                                   int* __restrict__ blockoff) {
    int tid = threadIdx.x;
    int v = (tid < NB_SCAN) ? blocksum[tid] : 0;
    int excl = block_excl_scan_256(v, tid, nullptr);
    if (tid < NB_SCAN) blockoff[tid] = excl;
}

__global__ __launch_bounds__(256) void scan_add_k(int* __restrict__ rowptr,
                                                  int* __restrict__ cursor,
                                                  const int* __restrict__ blockoff) {
    int gid = blockIdx.x * 256 + threadIdx.x;
    if (gid < N_NODES) {
        int r = rowptr[gid] + blockoff[blockIdx.x];
        rowptr[gid] = r;
        cursor[gid] = r;
    }
    if (gid == 0) rowptr[N_NODES] = N_EDGES;
}

__global__ void scatter_k(const int* __restrict__ src, const int* __restrict__ dst,
                          int* __restrict__ cursor, int* __restrict__ csr) {
    int i = blockIdx.x * blockDim.x + threadIdx.x;
    if (i < N_EDGES) {
        int d = dst[i];
        int pos = atomicAdd(&cursor[d], 1);
        csr[pos] = src[i];
    }
}

// ---------------- fp32 -> bf16 conversions ----------------

__global__ __launch_bounds__(256) void conv_bf_k(const float* __restrict__ in,
                                                 unsigned short* __restrict__ out, int n4) {
    int i = blockIdx.x * 256 + threadIdx.x;
    if (i >= n4) return;
    float4 v = *(const float4*)(in + (size_t)i * 4);
    uint32 lo = packbf(v.x, v.y);
    uint32 hi = packbf(v.z, v.w);
    uint2 o = {lo, hi};
    *(uint2*)(out + (size_t)i * 4) = o;
}

// Transpose+convert all weights. N=128 always. Block ranges hardcoded.
__global__ __launch_bounds__(256) void wconv_all_k(const float* W1e, const float* W2e,
                                                   const float* W1c, const float* W2c,
                                                   const float* Wm, const float* Wp1,
                                                   unsigned short* WT1e, unsigned short* WT2e,
                                                   unsigned short* WT1c, unsigned short* WT2c,
                                                   unsigned short* WTm1, unsigned short* WTm2,
                                                   unsigned short* WTp1) {
    int b = blockIdx.x;
    int t = threadIdx.x;
    const float* W; unsigned short* WT; int i; int K;
    if (b < 64)       { W = W1e; WT = WT1e; i = b * 256 + t;          K = 128; }
    else if (b < 128) { W = W2e; WT = WT2e; i = (b - 64) * 256 + t;   K = 128; }
    else if (b < 160) { W = W1c; WT = WT1c; i = (b - 128) * 256 + t;  K = 64;  }
    else if (b < 224) { W = W2c; WT = WT2c; i = (b - 160) * 256 + t;  K = 128; }
    else if (b < 352) { // Wm: 256x128, split into two K=128 halves
        i = (b - 224) * 256 + t;           // 0..32767
        int k = i >> 7, n = i & 127;
        unsigned short v = f2bf(Wm[i]);
        if (k < 128) WTm1[n * 128 + k] = v;
        else         WTm2[n * 128 + (k - 128)] = v;
        return;
    }
    else              { W = Wp1; WT = WTp1; i = (b - 352) * 256 + t;  K = 128; }
    int k = i >> 7, n = i & 127;   // i = k*128 + n
    if (k < K) WT[n * K + k] = f2bf(W[i]);
}

// ---------------- Aggregation (bf16): h[n] = (2+eps)*x[n] + sum x[src[e]] ----------------
// One wave per node; lane owns feature pair (2 bf16 in one u32).

__global__ __launch_bounds__(256) void agg128_bf_k(const uint32* __restrict__ X,
                                                   const int* __restrict__ rowptr,
                                                   const int* __restrict__ csr,
                                                   const float* __restrict__ eps,
                                                   uint32* __restrict__ H) {
    int wid = (blockIdx.x * 256 + threadIdx.x) >> 6;
    int lane = threadIdx.x & 63;
    if (wid >= N_NODES) return;
    float scale = 2.0f + eps[0];
    uint32 xv = X[(size_t)wid * 64 + lane];
    float a0 = scale * bflo(xv);
    float a1 = scale * bfhi(xv);
    int e0 = rowptr[wid], e1 = rowptr[wid + 1];
    for (int e = e0; e < e1; e++) {
        uint32 v = X[(size_t)csr[e] * 64 + lane];
        a0 += bflo(v);
        a1 += bfhi(v);
    }
    H[(size_t)wid * 64 + lane] = packbf(a0, a1);
}

// F=64: half-wave per node (32 lanes x u32 = 64 bf16).
__global__ __launch_bounds__(256) void agg64_bf_k(const uint32* __restrict__ X,
                                                  const int* __restrict__ rowptr,
                                                  const int* __restrict__ csr,
                                                  const float* __restrict__ eps,
                                                  uint32* __restrict__ H) {
    int hw = (blockIdx.x * 256 + threadIdx.x) >> 5;
    int lane = threadIdx.x & 31;
    if (hw >= N_NODES) return;
    float scale = 2.0f + eps[0];
    uint32 xv = X[(size_t)hw * 32 + lane];
    float a0 = scale * bflo(xv);
    float a1 = scale * bfhi(xv);
    int e0 = rowptr[hw], e1 = rowptr[hw + 1];
    for (int e = e0; e < e1; e++) {
        uint32 v = X[(size_t)csr[e] * 32 + lane];
        a0 += bflo(v);
        a1 += bfhi(v);
    }
    H[(size_t)hw * 32 + lane] = packbf(a0, a1);
}

// ---------------- MFMA bf16 GEMM: out[M x 128] = act(A1@W1 (+ A2@W2) + bias) ----------------
// A: [M][K] bf16 row-major. WT: [128][K] bf16 (pre-transposed). LDS-free: A-frags from
// global (rows private per block), B-frags from L2-resident WT. Both operands loaded with
// the SAME per-lane k-slot formula, so the ISA's k->slot mapping cancels (permutation arg).
// C/D mapping (m89/m91-verified): col = lane&15, row = (lane>>4)*4 + reg.
// Block: 256 thr = 4 waves; tile 32 rows x 128 cols; wave w: rows 16*(w&1), cols 64*(w>>1).

__global__ __launch_bounds__(256) void gemm_bf_k(const unsigned short* __restrict__ A1,
                                                 const unsigned short* __restrict__ WT1, int K1,
                                                 const unsigned short* __restrict__ A2,
                                                 const unsigned short* __restrict__ WT2, int K2,
                                                 const float* __restrict__ bias,
                                                 unsigned short* __restrict__ out, int act) {
    int tid = threadIdx.x;
    int w = tid >> 6, l = tid & 63;
    int row16 = blockIdx.x * 32 + (w & 1) * 16;
    int col16 = (w >> 1) * 64;
    int m = l & 15, g = l >> 4;

    f32x4 acc[4];
#pragma unroll
    for (int nt = 0; nt < 4; nt++) acc[nt] = (f32x4){0.f, 0.f, 0.f, 0.f};

    const unsigned short* A = A1;
    const unsigned short* WT = WT1;
    int K = K1;
    for (int pass = 0; pass < 2; ++pass) {
        if (pass) {
            if (A2 == nullptr) break;
            A = A2; WT = WT2; K = K2;
        }
        const unsigned short* ap = A + (size_t)(row16 + m) * K + g * 8;
        const unsigned short* bp = WT + (size_t)(col16 + m) * K + g * 8;
        for (int k0 = 0; k0 < K; k0 += 32) {
            bf16x8 af = *(const bf16x8*)(ap + k0);
#pragma unroll
            for (int nt = 0; nt < 4; nt++) {
                bf16x8 bfv = *(const bf16x8*)(bp + (size_t)nt * 16 * K + k0);
                acc[nt] = __builtin_amdgcn_mfma_f32_16x16x32_bf16(af, bfv, acc[nt], 0, 0, 0);
            }
        }
    }

#pragma unroll
    for (int nt = 0; nt < 4; nt++) {
        int col = col16 + nt * 16 + m;
        float bv = bias[col];
#pragma unroll
        for (int r = 0; r < 4; r++) {
            int row = row16 + g * 4 + r;
            if (row < N_NODES) {
                float v = acc[nt][r] + bv;
                if (act == 1) v = v > 0.f ? v : 0.2f * v;
                else if (act == 2) v = fmaxf(v, 0.f);
                out[(size_t)row * 128 + col] = f2bf(v);
            }
        }
    }
}

// ---------------- fused partial pooling over bf16 D and T ----------------

__global__ __launch_bounds__(64) void pool2_bf_k(const uint32* __restrict__ D,
                                                 const uint32* __restrict__ T,
                                                 const int* __restrict__ batch,
                                                 float* __restrict__ sumD,
                                                 float* __restrict__ sumT) {
    int f = threadIdx.x;  // pair index 0..63
    int i0 = blockIdx.x * PCHUNK;
    int i1 = min(i0 + PCHUNK, N_NODES);
    float d0 = 0.f, d1 = 0.f, t0 = 0.f, t1 = 0.f;
    int g = batch[i0];
    for (int i = i0; i < i1; i++) {
        int bg = batch[i];
        if (bg != g) {
            atomicAdd(&sumD[g * 128 + 2 * f], d0);
            atomicAdd(&sumD[g * 128 + 2 * f + 1], d1);
            atomicAdd(&sumT[g * 128 + 2 * f], t0);
            atomicAdd(&sumT[g * 128 + 2 * f + 1], t1);
            d0 = d1 = t0 = t1 = 0.f; g = bg;
        }
        uint32 dv = D[(size_t)i * 64 + f];
        uint32 tv = T[(size_t)i * 64 + f];
        d0 += bflo(dv); d1 += bfhi(dv);
        t0 += bflo(tv); t1 += bfhi(tv);
    }
    atomicAdd(&sumD[g * 128 + 2 * f], d0);
    atomicAdd(&sumD[g * 128 + 2 * f + 1], d1);
    atomicAdd(&sumT[g * 128 + 2 * f], t0);
    atomicAdd(&sumT[g * 128 + 2 * f + 1], t1);
}

// ---------------- finalize ----------------

__global__ __launch_bounds__(128) void finalize_k(const float* __restrict__ sumD,
                                                  const float* __restrict__ sumT,
                                                  const float* __restrict__ invcnt,
                                                  const float* __restrict__ Wp2,
                                                  const float* __restrict__ bp2,
                                                  float* __restrict__ out) {
    __shared__ float tr[128];
    int g = blockIdx.x;
    int f = threadIdx.x;
    float ic = invcnt[g];
    out[g * 128 + f] = sumD[g * 128 + f] * ic;
    tr[f] = sumT[g * 128 + f] * ic;
    __syncthreads();
    if (f < NCLS) {
        float acc = (ic > 0.f) ? bp2[f] : 0.f;
        for (int k = 0; k < 128; k++) acc = fmaf(tr[k], Wp2[k * NCLS + f], acc);
        out[NG * 128 + g * NCLS + f] = acc;
    }
}

// ---------------- launch ----------------

extern "C" void kernel_launch(void* const* d_in, const int* in_sizes, int n_in,
                              void* d_out, int out_size, void* d_ws, size_t ws_size,
                              hipStream_t stream) {
    const float* exp_f = (const float*)d_in[0];
    const float* cnv_f = (const float*)d_in[1];
    const int*   ei    = (const int*)d_in[2];
    const int*   batch = (const int*)d_in[3];
    const float* eps1e = (const float*)d_in[4];
    const float* W1e   = (const float*)d_in[5];
    const float* b1e   = (const float*)d_in[6];
    const float* eps2e = (const float*)d_in[7];
    const float* W2e   = (const float*)d_in[8];
    const float* b2e   = (const float*)d_in[9];
    const float* eps1c = (const float*)d_in[10];
    const float* W1c   = (const float*)d_in[11];
    const float* b1c   = (const float*)d_in[12];
    const float* eps2c = (const float*)d_in[13];
    const float* W2c   = (const float*)d_in[14];
    const float* b2c   = (const float*)d_in[15];
    const float* Wm    = (const float*)d_in[16];
    const float* bm    = (const float*)d_in[17];
    const float* Wp1   = (const float*)d_in[18];
    const float* bp1   = (const float*)d_in[19];
    const float* Wp2   = (const float*)d_in[20];
    const float* bp2   = (const float*)d_in[21];
    float* out = (float*)d_out;

    char* ws = (char*)d_ws;
    size_t off = 0;
    auto alloc = [&](size_t bytes) -> void* {
        void* p = ws + off;
        off = (off + bytes + 255) & ~(size_t)255;
        return p;
    };
    int* deg      = (int*)alloc((size_t)N_NODES * 4);
    int* rowptr   = (int*)alloc((size_t)(N_NODES + 1) * 4);
    int* cursor   = (int*)alloc((size_t)N_NODES * 4);
    int* csr      = (int*)alloc((size_t)N_EDGES * 4);
    int* gstart   = (int*)alloc((NG + 1) * 4);
    float* invcnt = (float*)alloc(NG * 4);
    int* blocksum = (int*)alloc(NB_SCAN * 4);
    int* blockoff = (int*)alloc(NB_SCAN * 4);
    float* sumD   = (float*)alloc((size_t)NG * 128 * 4);
    float* sumT   = (float*)alloc((size_t)NG * 128 * 4);

    unsigned short* Xe = (unsigned short*)alloc((size_t)N_PAD * 128 * 2);
    unsigned short* Xc = (unsigned short*)alloc((size_t)N_PAD * 64 * 2);
    unsigned short* E  = (unsigned short*)alloc((size_t)N_PAD * 64 * 2);
    unsigned short* A  = (unsigned short*)alloc((size_t)N_PAD * 128 * 2);
    unsigned short* B  = (unsigned short*)alloc((size_t)N_PAD * 128 * 2);
    unsigned short* C  = (unsigned short*)alloc((size_t)N_PAD * 128 * 2);
    unsigned short* D  = (unsigned short*)alloc((size_t)N_PAD * 128 * 2);
    unsigned short* T  = (unsigned short*)alloc((size_t)N_PAD * 128 * 2);

    unsigned short* WT1e = (unsigned short*)alloc(128 * 128 * 2);
    unsigned short* WT2e = (unsigned short*)alloc(128 * 128 * 2);
    unsigned short* WT1c = (unsigned short*)alloc(128 * 64 * 2);
    unsigned short* WT2c = (unsigned short*)alloc(128 * 128 * 2);
    unsigned short* WTm1 = (unsigned short*)alloc(128 * 128 * 2);
    unsigned short* WTm2 = (unsigned short*)alloc(128 * 128 * 2);
    unsigned short* WTp1 = (unsigned short*)alloc(128 * 128 * 2);

    const int* src = ei;
    const int* dst = ei + N_EDGES;

    hipMemsetAsync(deg, 0, (size_t)N_NODES * 4, stream);
    hipMemsetAsync(sumD, 0, (size_t)NG * 128 * 4 * 2, stream);  // sumD+sumT contiguous

    // CSR build + graph bounds
    count_edges_k<<<(N_EDGES + 255) / 256, 256, 0, stream>>>(dst, deg);
    gbounds_k<<<(N_NODES + 255) / 256, 256, 0, stream>>>(batch, gstart);
    scan_partial_k<<<NB_SCAN, 256, 0, stream>>>(deg, rowptr, blocksum);
    scan_root_k<<<1, 256, 0, stream>>>(blocksum, blockoff);
    scan_add_k<<<NB_SCAN, 256, 0, stream>>>(rowptr, cursor, blockoff);
    gfin_k<<<1, 64, 0, stream>>>(gstart, invcnt);
    scatter_k<<<(N_EDGES + 255) / 256, 256, 0, stream>>>(src, dst, cursor, csr);

    // conversions
    conv_bf_k<<<(N_NODES * 128 / 4 + 255) / 256, 256, 0, stream>>>(exp_f, Xe, N_NODES * 128 / 4);
    conv_bf_k<<<(N_NODES * 64 / 4 + 255) / 256, 256, 0, stream>>>(cnv_f, Xc, N_NODES * 64 / 4);
    wconv_all_k<<<416, 256, 0, stream>>>(W1e, W2e, W1c, W2c, Wm, Wp1,
                                         WT1e, WT2e, WT1c, WT2c, WTm1, WTm2, WTp1);

    const int AGG_GRID = (N_NODES * 64 + 255) / 256;
    const int AGG64_GRID = (N_NODES * 32 + 255) / 256;
    const int GEMM_GRID = (N_NODES + 31) / 32;  // 1563

    // exp branch
    agg128_bf_k<<<AGG_GRID, 256, 0, stream>>>((const uint32*)Xe, rowptr, csr, eps1e, (uint32*)A);
    gemm_bf_k<<<GEMM_GRID, 256, 0, stream>>>(A, WT1e, 128, nullptr, nullptr, 0, b1e, B, 1);
    agg128_bf_k<<<AGG_GRID, 256, 0, stream>>>((const uint32*)B, rowptr, csr, eps2e, (uint32*)A);
    gemm_bf_k<<<GEMM_GRID, 256, 0, stream>>>(A, WT2e, 128, nullptr, nullptr, 0, b2e, B, 1);
    // cnv branch
    agg64_bf_k<<<AGG64_GRID, 256, 0, stream>>>((const uint32*)Xc, rowptr, csr, eps1c, (uint32*)E);
    gemm_bf_k<<<GEMM_GRID, 256, 0, stream>>>(E, WT1c, 64, nullptr, nullptr, 0, b1c, C, 1);
    agg128_bf_k<<<AGG_GRID, 256, 0, stream>>>((const uint32*)C, rowptr, csr, eps2c, (uint32*)A);
    gemm_bf_k<<<GEMM_GRID, 256, 0, stream>>>(A, WT2c, 128, nullptr, nullptr, 0, b2c, C, 1);
    // mix: D = lrelu(B@Wm_top + C@Wm_bot + bm)
    gemm_bf_k<<<GEMM_GRID, 256, 0, stream>>>(B, WTm1, 128, C, WTm2, 128, bm, D, 1);
    // head pre-pool: T = relu(D@Wp1+bp1)
    gemm_bf_k<<<GEMM_GRID, 256, 0, stream>>>(D, WTp1, 128, nullptr, nullptr, 0, bp1, T, 2);
    // pooling + finalize (logits head applied post-pool)
    pool2_bf_k<<<(N_NODES + PCHUNK - 1) / PCHUNK, 64, 0, stream>>>((const uint32*)D, (const uint32*)T,
                                                                   batch, sumD, sumT);
    finalize_k<<<NG, 128, 0, stream>>>(sumD, sumT, invcnt, Wp2, bp2, out);
}

// Round 6
// 529.558 us; speedup vs baseline: 2.6880x; 1.3113x over previous
//
#include <hip/hip_runtime.h>

#define N_NODES 50000
#define N_PAD   50016          // padded rows so OOB tile loads stay in-buffer
#define N_EDGES 800000
#define HID 128
#define NCLS 10
#define NG 64
#define PCHUNK 128
#define NB_SCAN ((N_NODES + 255) / 256)   // 196

typedef unsigned int uint32;
typedef __attribute__((ext_vector_type(8))) short bf16x8;
typedef __attribute__((ext_vector_type(4))) float f32x4;

// ---- bf16 helpers ----
__device__ __forceinline__ unsigned short f2bf(float f) {
    uint32 u = __float_as_uint(f);
    uint32 r = u + 0x7fffu + ((u >> 16) & 1u);   // RNE
    return (unsigned short)(r >> 16);
}
__device__ __forceinline__ float bflo(uint32 v) { return __uint_as_float(v << 16); }
__device__ __forceinline__ float bfhi(uint32 v) { return __uint_as_float(v & 0xffff0000u); }
__device__ __forceinline__ uint32 packbf(float a, float b) {
    return (uint32)f2bf(a) | ((uint32)f2bf(b) << 16);
}

// ---------------- CSR build ----------------

__global__ void count_edges_k(const int* __restrict__ dst, int* __restrict__ deg) {
    int i = blockIdx.x * blockDim.x + threadIdx.x;
    if (i < N_EDGES) atomicAdd(&deg[dst[i]], 1);
}

__global__ void gbounds_k(const int* __restrict__ batch, int* __restrict__ gstart) {
    int i = blockIdx.x * blockDim.x + threadIdx.x;
    if (i >= N_NODES) return;
    int b = batch[i];
    int prev = (i == 0) ? -1 : batch[i - 1];
    for (int g = prev + 1; g <= b; g++) gstart[g] = i;
    if (i == N_NODES - 1) {
        for (int g = b + 1; g <= NG; g++) gstart[g] = N_NODES;
    }
}

__global__ void gfin_k(const int* __restrict__ gstart, float* __restrict__ invcnt) {
    int g = threadIdx.x;
    if (g < NG) {
        int c = gstart[g + 1] - gstart[g];
        invcnt[g] = (c > 0) ? 1.0f / (float)c : 0.0f;
    }
}

__device__ __forceinline__ int block_excl_scan_256(int v, int tid, int* total_out) {
    int lane = tid & 63, w = tid >> 6;
    int x = v;
#pragma unroll
    for (int off = 1; off < 64; off <<= 1) {
        int y = __shfl_up(x, off, 64);
        if (lane >= off) x += y;
    }
    __shared__ int wsum[4];
    if (lane == 63) wsum[w] = x;
    __syncthreads();
    int add = 0;
#pragma unroll
    for (int i = 0; i < 4; i++) add += (i < w) ? wsum[i] : 0;
    int total = wsum[0] + wsum[1] + wsum[2] + wsum[3];
    if (total_out) *total_out = total;
    return x - v + add;
}

__global__ __launch_bounds__(256) void scan_partial_k(const int* __restrict__ deg,
                                                      int* __restrict__ rowptr,
                                                      int* __restrict__ blocksum) {
    int tid = threadIdx.x;
    int gid = blockIdx.x * 256 + tid;
    int v = (gid < N_NODES) ? deg[gid] : 0;
    int total;
    int excl = block_excl_scan_256(v, tid, &total);
    if (gid < N_NODES) rowptr[gid] = excl;
    if (tid == 0) blocksum[blockIdx.x] = total;
}

__global__ __launch_bounds__(256) void scan_root_k(const int* __restrict__ blocksum,
                                                   int* __restrict__ blockoff) {
    int tid = threadIdx.x;
    int v = (tid < NB_SCAN) ? blocksum[tid] : 0;
    int excl = block_excl_scan_256(v, tid, nullptr);
    if (tid < NB_SCAN) blockoff[tid] = excl;
}

__global__ __launch_bounds__(256) void scan_add_k(int* __restrict__ rowptr,
                                                  int* __restrict__ cursor,
                                                  const int* __restrict__ blockoff) {
    int gid = blockIdx.x * 256 + threadIdx.x;
    if (gid < N_NODES) {
        int r = rowptr[gid] + blockoff[blockIdx.x];
        rowptr[gid] = r;
        cursor[gid] = r;
    }
    if (gid == 0) rowptr[N_NODES] = N_EDGES;
}

__global__ void scatter_k(const int* __restrict__ src, const int* __restrict__ dst,
                          int* __restrict__ cursor, int* __restrict__ csr) {
    int i = blockIdx.x * blockDim.x + threadIdx.x;
    if (i < N_EDGES) {
        int d = dst[i];
        int pos = atomicAdd(&cursor[d], 1);
        csr[pos] = src[i];
    }
}

// ---------------- fp32 -> bf16 conversions ----------------

__global__ __launch_bounds__(256) void conv_bf_k(const float* __restrict__ in,
                                                 unsigned short* __restrict__ out, int n4) {
    int i = blockIdx.x * 256 + threadIdx.x;
    if (i >= n4) return;
    float4 v = *(const float4*)(in + (size_t)i * 4);
    uint32 lo = packbf(v.x, v.y);
    uint32 hi = packbf(v.z, v.w);
    uint2 o = {lo, hi};
    *(uint2*)(out + (size_t)i * 4) = o;
}

// Transpose+convert all weights. N=128 always. Block ranges hardcoded.
__global__ __launch_bounds__(256) void wconv_all_k(const float* W1e, const float* W2e,
                                                   const float* W1c, const float* W2c,
                                                   const float* Wm, const float* Wp1,
                                                   unsigned short* WT1e, unsigned short* WT2e,
                                                   unsigned short* WT1c, unsigned short* WT2c,
                                                   unsigned short* WTm1, unsigned short* WTm2,
                                                   unsigned short* WTp1) {
    int b = blockIdx.x;
    int t = threadIdx.x;
    const float* W; unsigned short* WT; int i; int K;
    if (b < 64)       { W = W1e; WT = WT1e; i = b * 256 + t;          K = 128; }
    else if (b < 128) { W = W2e; WT = WT2e; i = (b - 64) * 256 + t;   K = 128; }
    else if (b < 160) { W = W1c; WT = WT1c; i = (b - 128) * 256 + t;  K = 64;  }
    else if (b < 224) { W = W2c; WT = WT2c; i = (b - 160) * 256 + t;  K = 128; }
    else if (b < 352) { // Wm: 256x128, split into two K=128 halves
        i = (b - 224) * 256 + t;           // 0..32767
        int k = i >> 7, n = i & 127;
        unsigned short v = f2bf(Wm[i]);
        if (k < 128) WTm1[n * 128 + k] = v;
        else         WTm2[n * 128 + (k - 128)] = v;
        return;
    }
    else              { W = Wp1; WT = WTp1; i = (b - 352) * 256 + t;  K = 128; }
    int k = i >> 7, n = i & 127;   // i = k*128 + n
    if (k < K) WT[n * K + k] = f2bf(W[i]);
}

// ---------------- Aggregation (bf16): h[n] = (2+eps)*x[n] + sum x[src[e]] ----------------
// One wave per node; lane owns feature pair (2 bf16 in one u32).
// Edge loop unrolled x8: 8 independent row gathers in flight per wave
// (breaks the load->use latency chain that bounded round 5 at ~78 us).

__global__ __launch_bounds__(256) void agg128_bf_k(const uint32* __restrict__ X,
                                                   const int* __restrict__ rowptr,
                                                   const int* __restrict__ csr,
                                                   const float* __restrict__ eps,
                                                   uint32* __restrict__ H) {
    int wid = (blockIdx.x * 256 + threadIdx.x) >> 6;
    int lane = threadIdx.x & 63;
    if (wid >= N_NODES) return;
    float scale = 2.0f + eps[0];
    uint32 xv = X[(size_t)wid * 64 + lane];
    float a0 = scale * bflo(xv);
    float a1 = scale * bfhi(xv);
    int e = rowptr[wid], e1 = rowptr[wid + 1];
    for (; e + 8 <= e1; e += 8) {
        int i0 = csr[e],     i1 = csr[e + 1], i2 = csr[e + 2], i3 = csr[e + 3];
        int i4 = csr[e + 4], i5 = csr[e + 5], i6 = csr[e + 6], i7 = csr[e + 7];
        uint32 v0 = X[(size_t)i0 * 64 + lane];
        uint32 v1 = X[(size_t)i1 * 64 + lane];
        uint32 v2 = X[(size_t)i2 * 64 + lane];
        uint32 v3 = X[(size_t)i3 * 64 + lane];
        uint32 v4 = X[(size_t)i4 * 64 + lane];
        uint32 v5 = X[(size_t)i5 * 64 + lane];
        uint32 v6 = X[(size_t)i6 * 64 + lane];
        uint32 v7 = X[(size_t)i7 * 64 + lane];
        a0 += bflo(v0) + bflo(v1) + bflo(v2) + bflo(v3) +
              bflo(v4) + bflo(v5) + bflo(v6) + bflo(v7);
        a1 += bfhi(v0) + bfhi(v1) + bfhi(v2) + bfhi(v3) +
              bfhi(v4) + bfhi(v5) + bfhi(v6) + bfhi(v7);
    }
    if (e + 4 <= e1) {
        int i0 = csr[e], i1 = csr[e + 1], i2 = csr[e + 2], i3 = csr[e + 3];
        uint32 v0 = X[(size_t)i0 * 64 + lane];
        uint32 v1 = X[(size_t)i1 * 64 + lane];
        uint32 v2 = X[(size_t)i2 * 64 + lane];
        uint32 v3 = X[(size_t)i3 * 64 + lane];
        a0 += bflo(v0) + bflo(v1) + bflo(v2) + bflo(v3);
        a1 += bfhi(v0) + bfhi(v1) + bfhi(v2) + bfhi(v3);
        e += 4;
    }
    for (; e < e1; e++) {
        uint32 v = X[(size_t)csr[e] * 64 + lane];
        a0 += bflo(v);
        a1 += bfhi(v);
    }
    H[(size_t)wid * 64 + lane] = packbf(a0, a1);
}

// F=64: half-wave per node (32 lanes x u32 = 64 bf16). Same x8 unroll.
__global__ __launch_bounds__(256) void agg64_bf_k(const uint32* __restrict__ X,
                                                  const int* __restrict__ rowptr,
                                                  const int* __restrict__ csr,
                                                  const float* __restrict__ eps,
                                                  uint32* __restrict__ H) {
    int hw = (blockIdx.x * 256 + threadIdx.x) >> 5;
    int lane = threadIdx.x & 31;
    if (hw >= N_NODES) return;
    float scale = 2.0f + eps[0];
    uint32 xv = X[(size_t)hw * 32 + lane];
    float a0 = scale * bflo(xv);
    float a1 = scale * bfhi(xv);
    int e = rowptr[hw], e1 = rowptr[hw + 1];
    for (; e + 8 <= e1; e += 8) {
        int i0 = csr[e],     i1 = csr[e + 1], i2 = csr[e + 2], i3 = csr[e + 3];
        int i4 = csr[e + 4], i5 = csr[e + 5], i6 = csr[e + 6], i7 = csr[e + 7];
        uint32 v0 = X[(size_t)i0 * 32 + lane];
        uint32 v1 = X[(size_t)i1 * 32 + lane];
        uint32 v2 = X[(size_t)i2 * 32 + lane];
        uint32 v3 = X[(size_t)i3 * 32 + lane];
        uint32 v4 = X[(size_t)i4 * 32 + lane];
        uint32 v5 = X[(size_t)i5 * 32 + lane];
        uint32 v6 = X[(size_t)i6 * 32 + lane];
        uint32 v7 = X[(size_t)i7 * 32 + lane];
        a0 += bflo(v0) + bflo(v1) + bflo(v2) + bflo(v3) +
              bflo(v4) + bflo(v5) + bflo(v6) + bflo(v7);
        a1 += bfhi(v0) + bfhi(v1) + bfhi(v2) + bfhi(v3) +
              bfhi(v4) + bfhi(v5) + bfhi(v6) + bfhi(v7);
    }
    if (e + 4 <= e1) {
        int i0 = csr[e], i1 = csr[e + 1], i2 = csr[e + 2], i3 = csr[e + 3];
        uint32 v0 = X[(size_t)i0 * 32 + lane];
        uint32 v1 = X[(size_t)i1 * 32 + lane];
        uint32 v2 = X[(size_t)i2 * 32 + lane];
        uint32 v3 = X[(size_t)i3 * 32 + lane];
        a0 += bflo(v0) + bflo(v1) + bflo(v2) + bflo(v3);
        a1 += bfhi(v0) + bfhi(v1) + bfhi(v2) + bfhi(v3);
        e += 4;
    }
    for (; e < e1; e++) {
        uint32 v = X[(size_t)csr[e] * 32 + lane];
        a0 += bflo(v);
        a1 += bfhi(v);
    }
    H[(size_t)hw * 32 + lane] = packbf(a0, a1);
}

// ---------------- MFMA bf16 GEMM: out[M x 128] = act(A1@W1 (+ A2@W2) + bias) ----------------
// LDS-free; operands loaded with matching per-lane k-slot formula (permutation cancels).
// C/D mapping (m89/m91-verified): col = lane&15, row = (lane>>4)*4 + reg.

__global__ __launch_bounds__(256) void gemm_bf_k(const unsigned short* __restrict__ A1,
                                                 const unsigned short* __restrict__ WT1, int K1,
                                                 const unsigned short* __restrict__ A2,
                                                 const unsigned short* __restrict__ WT2, int K2,
                                                 const float* __restrict__ bias,
                                                 unsigned short* __restrict__ out, int act) {
    int tid = threadIdx.x;
    int w = tid >> 6, l = tid & 63;
    int row16 = blockIdx.x * 32 + (w & 1) * 16;
    int col16 = (w >> 1) * 64;
    int m = l & 15, g = l >> 4;

    f32x4 acc[4];
#pragma unroll
    for (int nt = 0; nt < 4; nt++) acc[nt] = (f32x4){0.f, 0.f, 0.f, 0.f};

    const unsigned short* A = A1;
    const unsigned short* WT = WT1;
    int K = K1;
    for (int pass = 0; pass < 2; ++pass) {
        if (pass) {
            if (A2 == nullptr) break;
            A = A2; WT = WT2; K = K2;
        }
        const unsigned short* ap = A + (size_t)(row16 + m) * K + g * 8;
        const unsigned short* bp = WT + (size_t)(col16 + m) * K + g * 8;
        for (int k0 = 0; k0 < K; k0 += 32) {
            bf16x8 af = *(const bf16x8*)(ap + k0);
#pragma unroll
            for (int nt = 0; nt < 4; nt++) {
                bf16x8 bfv = *(const bf16x8*)(bp + (size_t)nt * 16 * K + k0);
                acc[nt] = __builtin_amdgcn_mfma_f32_16x16x32_bf16(af, bfv, acc[nt], 0, 0, 0);
            }
        }
    }

#pragma unroll
    for (int nt = 0; nt < 4; nt++) {
        int col = col16 + nt * 16 + m;
        float bv = bias[col];
#pragma unroll
        for (int r = 0; r < 4; r++) {
            int row = row16 + g * 4 + r;
            if (row < N_NODES) {
                float v = acc[nt][r] + bv;
                if (act == 1) v = v > 0.f ? v : 0.2f * v;
                else if (act == 2) v = fmaxf(v, 0.f);
                out[(size_t)row * 128 + col] = f2bf(v);
            }
        }
    }
}

// ---------------- fused partial pooling over bf16 D and T ----------------

__global__ __launch_bounds__(64) void pool2_bf_k(const uint32* __restrict__ D,
                                                 const uint32* __restrict__ T,
                                                 const int* __restrict__ batch,
                                                 float* __restrict__ sumD,
                                                 float* __restrict__ sumT) {
    int f = threadIdx.x;  // pair index 0..63
    int i0 = blockIdx.x * PCHUNK;
    int i1 = min(i0 + PCHUNK, N_NODES);
    float d0 = 0.f, d1 = 0.f, t0 = 0.f, t1 = 0.f;
    int g = batch[i0];
    for (int i = i0; i < i1; i++) {
        int bg = batch[i];
        if (bg != g) {
            atomicAdd(&sumD[g * 128 + 2 * f], d0);
            atomicAdd(&sumD[g * 128 + 2 * f + 1], d1);
            atomicAdd(&sumT[g * 128 + 2 * f], t0);
            atomicAdd(&sumT[g * 128 + 2 * f + 1], t1);
            d0 = d1 = t0 = t1 = 0.f; g = bg;
        }
        uint32 dv = D[(size_t)i * 64 + f];
        uint32 tv = T[(size_t)i * 64 + f];
        d0 += bflo(dv); d1 += bfhi(dv);
        t0 += bflo(tv); t1 += bfhi(tv);
    }
    atomicAdd(&sumD[g * 128 + 2 * f], d0);
    atomicAdd(&sumD[g * 128 + 2 * f + 1], d1);
    atomicAdd(&sumT[g * 128 + 2 * f], t0);
    atomicAdd(&sumT[g * 128 + 2 * f + 1], t1);
}

// ---------------- finalize ----------------

__global__ __launch_bounds__(128) void finalize_k(const float* __restrict__ sumD,
                                                  const float* __restrict__ sumT,
                                                  const float* __restrict__ invcnt,
                                                  const float* __restrict__ Wp2,
                                                  const float* __restrict__ bp2,
                                                  float* __restrict__ out) {
    __shared__ float tr[128];
    int g = blockIdx.x;
    int f = threadIdx.x;
    float ic = invcnt[g];
    out[g * 128 + f] = sumD[g * 128 + f] * ic;
    tr[f] = sumT[g * 128 + f] * ic;
    __syncthreads();
    if (f < NCLS) {
        float acc = (ic > 0.f) ? bp2[f] : 0.f;
        for (int k = 0; k < 128; k++) acc = fmaf(tr[k], Wp2[k * NCLS + f], acc);
        out[NG * 128 + g * NCLS + f] = acc;
    }
}

// ---------------- launch ----------------

extern "C" void kernel_launch(void* const* d_in, const int* in_sizes, int n_in,
                              void* d_out, int out_size, void* d_ws, size_t ws_size,
                              hipStream_t stream) {
    const float* exp_f = (const float*)d_in[0];
    const float* cnv_f = (const float*)d_in[1];
    const int*   ei    = (const int*)d_in[2];
    const int*   batch = (const int*)d_in[3];
    const float* eps1e = (const float*)d_in[4];
    const float* W1e   = (const float*)d_in[5];
    const float* b1e   = (const float*)d_in[6];
    const float* eps2e = (const float*)d_in[7];
    const float* W2e   = (const float*)d_in[8];
    const float* b2e   = (const float*)d_in[9];
    const float* eps1c = (const float*)d_in[10];
    const float* W1c   = (const float*)d_in[11];
    const float* b1c   = (const float*)d_in[12];
    const float* eps2c = (const float*)d_in[13];
    const float* W2c   = (const float*)d_in[14];
    const float* b2c   = (const float*)d_in[15];
    const float* Wm    = (const float*)d_in[16];
    const float* bm    = (const float*)d_in[17];
    const float* Wp1   = (const float*)d_in[18];
    const float* bp1   = (const float*)d_in[19];
    const float* Wp2   = (const float*)d_in[20];
    const float* bp2   = (const float*)d_in[21];
    float* out = (float*)d_out;

    char* ws = (char*)d_ws;
    size_t off = 0;
    auto alloc = [&](size_t bytes) -> void* {
        void* p = ws + off;
        off = (off + bytes + 255) & ~(size_t)255;
        return p;
    };
    int* deg      = (int*)alloc((size_t)N_NODES * 4);
    int* rowptr   = (int*)alloc((size_t)(N_NODES + 1) * 4);
    int* cursor   = (int*)alloc((size_t)N_NODES * 4);
    int* csr      = (int*)alloc((size_t)N_EDGES * 4);
    int* gstart   = (int*)alloc((NG + 1) * 4);
    float* invcnt = (float*)alloc(NG * 4);
    int* blocksum = (int*)alloc(NB_SCAN * 4);
    int* blockoff = (int*)alloc(NB_SCAN * 4);
    float* sumD   = (float*)alloc((size_t)NG * 128 * 4);
    float* sumT   = (float*)alloc((size_t)NG * 128 * 4);

    unsigned short* Xe = (unsigned short*)alloc((size_t)N_PAD * 128 * 2);
    unsigned short* Xc = (unsigned short*)alloc((size_t)N_PAD * 64 * 2);
    unsigned short* E  = (unsigned short*)alloc((size_t)N_PAD * 64 * 2);
    unsigned short* A  = (unsigned short*)alloc((size_t)N_PAD * 128 * 2);
    unsigned short* B  = (unsigned short*)alloc((size_t)N_PAD * 128 * 2);
    unsigned short* C  = (unsigned short*)alloc((size_t)N_PAD * 128 * 2);
    unsigned short* D  = (unsigned short*)alloc((size_t)N_PAD * 128 * 2);
    unsigned short* T  = (unsigned short*)alloc((size_t)N_PAD * 128 * 2);

    unsigned short* WT1e = (unsigned short*)alloc(128 * 128 * 2);
    unsigned short* WT2e = (unsigned short*)alloc(128 * 128 * 2);
    unsigned short* WT1c = (unsigned short*)alloc(128 * 64 * 2);
    unsigned short* WT2c = (unsigned short*)alloc(128 * 128 * 2);
    unsigned short* WTm1 = (unsigned short*)alloc(128 * 128 * 2);
    unsigned short* WTm2 = (unsigned short*)alloc(128 * 128 * 2);
    unsigned short* WTp1 = (unsigned short*)alloc(128 * 128 * 2);

    const int* src = ei;
    const int* dst = ei + N_EDGES;

    hipMemsetAsync(deg, 0, (size_t)N_NODES * 4, stream);
    hipMemsetAsync(sumD, 0, (size_t)NG * 128 * 4 * 2, stream);  // sumD+sumT contiguous

    // CSR build + graph bounds
    count_edges_k<<<(N_EDGES + 255) / 256, 256, 0, stream>>>(dst, deg);
    gbounds_k<<<(N_NODES + 255) / 256, 256, 0, stream>>>(batch, gstart);
    scan_partial_k<<<NB_SCAN, 256, 0, stream>>>(deg, rowptr, blocksum);
    scan_root_k<<<1, 256, 0, stream>>>(blocksum, blockoff);
    scan_add_k<<<NB_SCAN, 256, 0, stream>>>(rowptr, cursor, blockoff);
    gfin_k<<<1, 64, 0, stream>>>(gstart, invcnt);
    scatter_k<<<(N_EDGES + 255) / 256, 256, 0, stream>>>(src, dst, cursor, csr);

    // conversions
    conv_bf_k<<<(N_NODES * 128 / 4 + 255) / 256, 256, 0, stream>>>(exp_f, Xe, N_NODES * 128 / 4);
    conv_bf_k<<<(N_NODES * 64 / 4 + 255) / 256, 256, 0, stream>>>(cnv_f, Xc, N_NODES * 64 / 4);
    wconv_all_k<<<416, 256, 0, stream>>>(W1e, W2e, W1c, W2c, Wm, Wp1,
                                         WT1e, WT2e, WT1c, WT2c, WTm1, WTm2, WTp1);

    const int AGG_GRID = (N_NODES * 64 + 255) / 256;
    const int AGG64_GRID = (N_NODES * 32 + 255) / 256;
    const int GEMM_GRID = (N_NODES + 31) / 32;  // 1563

    // exp branch
    agg128_bf_k<<<AGG_GRID, 256, 0, stream>>>((const uint32*)Xe, rowptr, csr, eps1e, (uint32*)A);
    gemm_bf_k<<<GEMM_GRID, 256, 0, stream>>>(A, WT1e, 128, nullptr, nullptr, 0, b1e, B, 1);
    agg128_bf_k<<<AGG_GRID, 256, 0, stream>>>((const uint32*)B, rowptr, csr, eps2e, (uint32*)A);
    gemm_bf_k<<<GEMM_GRID, 256, 0, stream>>>(A, WT2e, 128, nullptr, nullptr, 0, b2e, B, 1);
    // cnv branch
    agg64_bf_k<<<AGG64_GRID, 256, 0, stream>>>((const uint32*)Xc, rowptr, csr, eps1c, (uint32*)E);
    gemm_bf_k<<<GEMM_GRID, 256, 0, stream>>>(E, WT1c, 64, nullptr, nullptr, 0, b1c, C, 1);
    agg128_bf_k<<<AGG_GRID, 256, 0, stream>>>((const uint32*)C, rowptr, csr, eps2c, (uint32*)A);
    gemm_bf_k<<<GEMM_GRID, 256, 0, stream>>>(A, WT2c, 128, nullptr, nullptr, 0, b2c, C, 1);
    // mix: D = lrelu(B@Wm_top + C@Wm_bot + bm)
    gemm_bf_k<<<GEMM_GRID, 256, 0, stream>>>(B, WTm1, 128, C, WTm2, 128, bm, D, 1);
    // head pre-pool: T = relu(D@Wp1+bp1)
    gemm_bf_k<<<GEMM_GRID, 256, 0, stream>>>(D, WTp1, 128, nullptr, nullptr, 0, bp1, T, 2);
    // pooling + finalize (logits head applied post-pool)
    pool2_bf_k<<<(N_NODES + PCHUNK - 1) / PCHUNK, 64, 0, stream>>>((const uint32*)D, (const uint32*)T,
                                                                   batch, sumD, sumT);
    finalize_k<<<NG, 128, 0, stream>>>(sumD, sumT, invcnt, Wp2, bp2, out);
}

// Round 7
// 522.030 us; speedup vs baseline: 2.7267x; 1.0144x over previous
//
#include <hip/hip_runtime.h>

#define N_NODES 50000
#define N_PAD   50016          // padded rows so OOB tile loads stay in-buffer
#define N_EDGES 800000
#define HID 128
#define NCLS 10
#define NG 64
#define PCHUNK 128
#define NB_SCAN ((N_NODES + 255) / 256)   // 196

// XCD-partitioned edge processing
#define EPART 8
#define PRANGE ((N_NODES + EPART - 1) / EPART)       // 6250 nodes per partition
#define ECHUNK 4096
#define NCHUNK ((N_EDGES + ECHUNK - 1) / ECHUNK)     // 196 chunks

typedef unsigned int uint32;
typedef __attribute__((ext_vector_type(8))) short bf16x8;
typedef __attribute__((ext_vector_type(4))) float f32x4;

// ---- bf16 helpers ----
__device__ __forceinline__ unsigned short f2bf(float f) {
    uint32 u = __float_as_uint(f);
    uint32 r = u + 0x7fffu + ((u >> 16) & 1u);   // RNE
    return (unsigned short)(r >> 16);
}
__device__ __forceinline__ float bflo(uint32 v) { return __uint_as_float(v << 16); }
__device__ __forceinline__ float bfhi(uint32 v) { return __uint_as_float(v & 0xffff0000u); }
__device__ __forceinline__ uint32 packbf(float a, float b) {
    return (uint32)f2bf(a) | ((uint32)f2bf(b) << 16);
}

// ---------------- CSR build (XCD-partitioned by dst range) ----------------
// Block b: reads edge chunk b>>3, handles only dst in partition b&7.
// With round-robin block->XCD dispatch, each partition's deg/cursor/csr slice
// stays in ONE XCD's L2 -> atomics are local, csr lines written back once
// (round 6: scatter WRITE_SIZE was 52 MB for 3.2 MB of logical csr data).

__global__ __launch_bounds__(256) void count_part_k(const int* __restrict__ dst,
                                                    int* __restrict__ deg) {
    int part = blockIdx.x & 7;
    int chunk = blockIdx.x >> 3;
    int lo = part * PRANGE;
    int hi = min(lo + PRANGE, N_NODES);
    int e0 = chunk * ECHUNK;
    int e1 = min(e0 + ECHUNK, N_EDGES);
    for (int i = e0 + threadIdx.x; i < e1; i += 256) {
        int d = dst[i];
        if (d >= lo && d < hi) atomicAdd(&deg[d], 1);
    }
}

__global__ __launch_bounds__(256) void scatter_part_k(const int* __restrict__ src,
                                                      const int* __restrict__ dst,
                                                      int* __restrict__ cursor,
                                                      int* __restrict__ csr) {
    int part = blockIdx.x & 7;
    int chunk = blockIdx.x >> 3;
    int lo = part * PRANGE;
    int hi = min(lo + PRANGE, N_NODES);
    int e0 = chunk * ECHUNK;
    int e1 = min(e0 + ECHUNK, N_EDGES);
    for (int i = e0 + threadIdx.x; i < e1; i += 256) {
        int d = dst[i];
        if (d >= lo && d < hi) {
            int pos = atomicAdd(&cursor[d], 1);
            csr[pos] = src[i];
        }
    }
}

__global__ void gbounds_k(const int* __restrict__ batch, int* __restrict__ gstart) {
    int i = blockIdx.x * blockDim.x + threadIdx.x;
    if (i >= N_NODES) return;
    int b = batch[i];
    int prev = (i == 0) ? -1 : batch[i - 1];
    for (int g = prev + 1; g <= b; g++) gstart[g] = i;
    if (i == N_NODES - 1) {
        for (int g = b + 1; g <= NG; g++) gstart[g] = N_NODES;
    }
}

__global__ void gfin_k(const int* __restrict__ gstart, float* __restrict__ invcnt) {
    int g = threadIdx.x;
    if (g < NG) {
        int c = gstart[g + 1] - gstart[g];
        invcnt[g] = (c > 0) ? 1.0f / (float)c : 0.0f;
    }
}

__device__ __forceinline__ int block_excl_scan_256(int v, int tid, int* total_out) {
    int lane = tid & 63, w = tid >> 6;
    int x = v;
#pragma unroll
    for (int off = 1; off < 64; off <<= 1) {
        int y = __shfl_up(x, off, 64);
        if (lane >= off) x += y;
    }
    __shared__ int wsum[4];
    if (lane == 63) wsum[w] = x;
    __syncthreads();
    int add = 0;
#pragma unroll
    for (int i = 0; i < 4; i++) add += (i < w) ? wsum[i] : 0;
    int total = wsum[0] + wsum[1] + wsum[2] + wsum[3];
    if (total_out) *total_out = total;
    return x - v + add;
}

__global__ __launch_bounds__(256) void scan_partial_k(const int* __restrict__ deg,
                                                      int* __restrict__ rowptr,
                                                      int* __restrict__ blocksum) {
    int tid = threadIdx.x;
    int gid = blockIdx.x * 256 + tid;
    int v = (gid < N_NODES) ? deg[gid] : 0;
    int total;
    int excl = block_excl_scan_256(v, tid, &total);
    if (gid < N_NODES) rowptr[gid] = excl;
    if (tid == 0) blocksum[blockIdx.x] = total;
}

__global__ __launch_bounds__(256) void scan_root_k(const int* __restrict__ blocksum,
                                                   int* __restrict__ blockoff) {
    int tid = threadIdx.x;
    int v = (tid < NB_SCAN) ? blocksum[tid] : 0;
    int excl = block_excl_scan_256(v, tid, nullptr);
    if (tid < NB_SCAN) blockoff[tid] = excl;
}

__global__ __launch_bounds__(256) void scan_add_k(int* __restrict__ rowptr,
                                                  int* __restrict__ cursor,
                                                  const int* __restrict__ blockoff) {
    int gid = blockIdx.x * 256 + threadIdx.x;
    if (gid < N_NODES) {
        int r = rowptr[gid] + blockoff[blockIdx.x];
        rowptr[gid] = r;
        cursor[gid] = r;
    }
    if (gid == 0) rowptr[N_NODES] = N_EDGES;
}

// ---------------- fp32 -> bf16 conversions ----------------

__global__ __launch_bounds__(256) void conv_bf_k(const float* __restrict__ in,
                                                 unsigned short* __restrict__ out, int n4) {
    int i = blockIdx.x * 256 + threadIdx.x;
    if (i >= n4) return;
    float4 v = *(const float4*)(in + (size_t)i * 4);
    uint32 lo = packbf(v.x, v.y);
    uint32 hi = packbf(v.z, v.w);
    uint2 o = {lo, hi};
    *(uint2*)(out + (size_t)i * 4) = o;
}

// Transpose+convert all weights. N=128 always. Block ranges hardcoded.
__global__ __launch_bounds__(256) void wconv_all_k(const float* W1e, const float* W2e,
                                                   const float* W1c, const float* W2c,
                                                   const float* Wm, const float* Wp1,
                                                   unsigned short* WT1e, unsigned short* WT2e,
                                                   unsigned short* WT1c, unsigned short* WT2c,
                                                   unsigned short* WTm1, unsigned short* WTm2,
                                                   unsigned short* WTp1) {
    int b = blockIdx.x;
    int t = threadIdx.x;
    const float* W; unsigned short* WT; int i; int K;
    if (b < 64)       { W = W1e; WT = WT1e; i = b * 256 + t;          K = 128; }
    else if (b < 128) { W = W2e; WT = WT2e; i = (b - 64) * 256 + t;   K = 128; }
    else if (b < 160) { W = W1c; WT = WT1c; i = (b - 128) * 256 + t;  K = 64;  }
    else if (b < 224) { W = W2c; WT = WT2c; i = (b - 160) * 256 + t;  K = 128; }
    else if (b < 352) { // Wm: 256x128, split into two K=128 halves
        i = (b - 224) * 256 + t;           // 0..32767
        int k = i >> 7, n = i & 127;
        unsigned short v = f2bf(Wm[i]);
        if (k < 128) WTm1[n * 128 + k] = v;
        else         WTm2[n * 128 + (k - 128)] = v;
        return;
    }
    else              { W = Wp1; WT = WTp1; i = (b - 352) * 256 + t;  K = 128; }
    int k = i >> 7, n = i & 127;   // i = k*128 + n
    if (k < K) WT[n * K + k] = f2bf(W[i]);
}

// ---------------- Aggregation (bf16): h[n] = (2+eps)*x[n] + sum x[src[e]] ----------------
// One wave per node; lane owns feature pair. Edge loop unrolled x8 for MLP
// (8 independent gathers in flight; round 5->6: 78.6 -> ~30 us).

__global__ __launch_bounds__(256) void agg128_bf_k(const uint32* __restrict__ X,
                                                   const int* __restrict__ rowptr,
                                                   const int* __restrict__ csr,
                                                   const float* __restrict__ eps,
                                                   uint32* __restrict__ H) {
    int wid = (blockIdx.x * 256 + threadIdx.x) >> 6;
    int lane = threadIdx.x & 63;
    if (wid >= N_NODES) return;
    float scale = 2.0f + eps[0];
    uint32 xv = X[(size_t)wid * 64 + lane];
    float a0 = scale * bflo(xv);
    float a1 = scale * bfhi(xv);
    int e = rowptr[wid], e1 = rowptr[wid + 1];
    for (; e + 8 <= e1; e += 8) {
        int i0 = csr[e],     i1 = csr[e + 1], i2 = csr[e + 2], i3 = csr[e + 3];
        int i4 = csr[e + 4], i5 = csr[e + 5], i6 = csr[e + 6], i7 = csr[e + 7];
        uint32 v0 = X[(size_t)i0 * 64 + lane];
        uint32 v1 = X[(size_t)i1 * 64 + lane];
        uint32 v2 = X[(size_t)i2 * 64 + lane];
        uint32 v3 = X[(size_t)i3 * 64 + lane];
        uint32 v4 = X[(size_t)i4 * 64 + lane];
        uint32 v5 = X[(size_t)i5 * 64 + lane];
        uint32 v6 = X[(size_t)i6 * 64 + lane];
        uint32 v7 = X[(size_t)i7 * 64 + lane];
        a0 += bflo(v0) + bflo(v1) + bflo(v2) + bflo(v3) +
              bflo(v4) + bflo(v5) + bflo(v6) + bflo(v7);
        a1 += bfhi(v0) + bfhi(v1) + bfhi(v2) + bfhi(v3) +
              bfhi(v4) + bfhi(v5) + bfhi(v6) + bfhi(v7);
    }
    if (e + 4 <= e1) {
        int i0 = csr[e], i1 = csr[e + 1], i2 = csr[e + 2], i3 = csr[e + 3];
        uint32 v0 = X[(size_t)i0 * 64 + lane];
        uint32 v1 = X[(size_t)i1 * 64 + lane];
        uint32 v2 = X[(size_t)i2 * 64 + lane];
        uint32 v3 = X[(size_t)i3 * 64 + lane];
        a0 += bflo(v0) + bflo(v1) + bflo(v2) + bflo(v3);
        a1 += bfhi(v0) + bfhi(v1) + bfhi(v2) + bfhi(v3);
        e += 4;
    }
    for (; e < e1; e++) {
        uint32 v = X[(size_t)csr[e] * 64 + lane];
        a0 += bflo(v);
        a1 += bfhi(v);
    }
    H[(size_t)wid * 64 + lane] = packbf(a0, a1);
}

// F=64: half-wave per node (32 lanes x u32 = 64 bf16). Same x8 unroll.
__global__ __launch_bounds__(256) void agg64_bf_k(const uint32* __restrict__ X,
                                                  const int* __restrict__ rowptr,
                                                  const int* __restrict__ csr,
                                                  const float* __restrict__ eps,
                                                  uint32* __restrict__ H) {
    int hw = (blockIdx.x * 256 + threadIdx.x) >> 5;
    int lane = threadIdx.x & 31;
    if (hw >= N_NODES) return;
    float scale = 2.0f + eps[0];
    uint32 xv = X[(size_t)hw * 32 + lane];
    float a0 = scale * bflo(xv);
    float a1 = scale * bfhi(xv);
    int e = rowptr[hw], e1 = rowptr[hw + 1];
    for (; e + 8 <= e1; e += 8) {
        int i0 = csr[e],     i1 = csr[e + 1], i2 = csr[e + 2], i3 = csr[e + 3];
        int i4 = csr[e + 4], i5 = csr[e + 5], i6 = csr[e + 6], i7 = csr[e + 7];
        uint32 v0 = X[(size_t)i0 * 32 + lane];
        uint32 v1 = X[(size_t)i1 * 32 + lane];
        uint32 v2 = X[(size_t)i2 * 32 + lane];
        uint32 v3 = X[(size_t)i3 * 32 + lane];
        uint32 v4 = X[(size_t)i4 * 32 + lane];
        uint32 v5 = X[(size_t)i5 * 32 + lane];
        uint32 v6 = X[(size_t)i6 * 32 + lane];
        uint32 v7 = X[(size_t)i7 * 32 + lane];
        a0 += bflo(v0) + bflo(v1) + bflo(v2) + bflo(v3) +
              bflo(v4) + bflo(v5) + bflo(v6) + bflo(v7);
        a1 += bfhi(v0) + bfhi(v1) + bfhi(v2) + bfhi(v3) +
              bfhi(v4) + bfhi(v5) + bfhi(v6) + bfhi(v7);
    }
    if (e + 4 <= e1) {
        int i0 = csr[e], i1 = csr[e + 1], i2 = csr[e + 2], i3 = csr[e + 3];
        uint32 v0 = X[(size_t)i0 * 32 + lane];
        uint32 v1 = X[(size_t)i1 * 32 + lane];
        uint32 v2 = X[(size_t)i2 * 32 + lane];
        uint32 v3 = X[(size_t)i3 * 32 + lane];
        a0 += bflo(v0) + bflo(v1) + bflo(v2) + bflo(v3);
        a1 += bfhi(v0) + bfhi(v1) + bfhi(v2) + bfhi(v3);
        e += 4;
    }
    for (; e < e1; e++) {
        uint32 v = X[(size_t)csr[e] * 32 + lane];
        a0 += bflo(v);
        a1 += bfhi(v);
    }
    H[(size_t)hw * 32 + lane] = packbf(a0, a1);
}

// ---------------- MFMA bf16 GEMM: out[M x 128] = act(A1@W1 (+ A2@W2) + bias) ----------------
// LDS-free; operands loaded with matching per-lane k-slot formula (permutation cancels).
// C/D mapping (m89/m91-verified): col = lane&15, row = (lane>>4)*4 + reg.

__global__ __launch_bounds__(256) void gemm_bf_k(const unsigned short* __restrict__ A1,
                                                 const unsigned short* __restrict__ WT1, int K1,
                                                 const unsigned short* __restrict__ A2,
                                                 const unsigned short* __restrict__ WT2, int K2,
                                                 const float* __restrict__ bias,
                                                 unsigned short* __restrict__ out, int act) {
    int tid = threadIdx.x;
    int w = tid >> 6, l = tid & 63;
    int row16 = blockIdx.x * 32 + (w & 1) * 16;
    int col16 = (w >> 1) * 64;
    int m = l & 15, g = l >> 4;

    f32x4 acc[4];
#pragma unroll
    for (int nt = 0; nt < 4; nt++) acc[nt] = (f32x4){0.f, 0.f, 0.f, 0.f};

    const unsigned short* A = A1;
    const unsigned short* WT = WT1;
    int K = K1;
    for (int pass = 0; pass < 2; ++pass) {
        if (pass) {
            if (A2 == nullptr) break;
            A = A2; WT = WT2; K = K2;
        }
        const unsigned short* ap = A + (size_t)(row16 + m) * K + g * 8;
        const unsigned short* bp = WT + (size_t)(col16 + m) * K + g * 8;
        for (int k0 = 0; k0 < K; k0 += 32) {
            bf16x8 af = *(const bf16x8*)(ap + k0);
#pragma unroll
            for (int nt = 0; nt < 4; nt++) {
                bf16x8 bfv = *(const bf16x8*)(bp + (size_t)nt * 16 * K + k0);
                acc[nt] = __builtin_amdgcn_mfma_f32_16x16x32_bf16(af, bfv, acc[nt], 0, 0, 0);
            }
        }
    }

#pragma unroll
    for (int nt = 0; nt < 4; nt++) {
        int col = col16 + nt * 16 + m;
        float bv = bias[col];
#pragma unroll
        for (int r = 0; r < 4; r++) {
            int row = row16 + g * 4 + r;
            if (row < N_NODES) {
                float v = acc[nt][r] + bv;
                if (act == 1) v = v > 0.f ? v : 0.2f * v;
                else if (act == 2) v = fmaxf(v, 0.f);
                out[(size_t)row * 128 + col] = f2bf(v);
            }
        }
    }
}

// ---------------- fused partial pooling over bf16 D and T ----------------

__global__ __launch_bounds__(64) void pool2_bf_k(const uint32* __restrict__ D,
                                                 const uint32* __restrict__ T,
                                                 const int* __restrict__ batch,
                                                 float* __restrict__ sumD,
                                                 float* __restrict__ sumT) {
    int f = threadIdx.x;  // pair index 0..63
    int i0 = blockIdx.x * PCHUNK;
    int i1 = min(i0 + PCHUNK, N_NODES);
    float d0 = 0.f, d1 = 0.f, t0 = 0.f, t1 = 0.f;
    int g = batch[i0];
    for (int i = i0; i < i1; i++) {
        int bg = batch[i];
        if (bg != g) {
            atomicAdd(&sumD[g * 128 + 2 * f], d0);
            atomicAdd(&sumD[g * 128 + 2 * f + 1], d1);
            atomicAdd(&sumT[g * 128 + 2 * f], t0);
            atomicAdd(&sumT[g * 128 + 2 * f + 1], t1);
            d0 = d1 = t0 = t1 = 0.f; g = bg;
        }
        uint32 dv = D[(size_t)i * 64 + f];
        uint32 tv = T[(size_t)i * 64 + f];
        d0 += bflo(dv); d1 += bfhi(dv);
        t0 += bflo(tv); t1 += bfhi(tv);
    }
    atomicAdd(&sumD[g * 128 + 2 * f], d0);
    atomicAdd(&sumD[g * 128 + 2 * f + 1], d1);
    atomicAdd(&sumT[g * 128 + 2 * f], t0);
    atomicAdd(&sumT[g * 128 + 2 * f + 1], t1);
}

// ---------------- finalize ----------------

__global__ __launch_bounds__(128) void finalize_k(const float* __restrict__ sumD,
                                                  const float* __restrict__ sumT,
                                                  const float* __restrict__ invcnt,
                                                  const float* __restrict__ Wp2,
                                                  const float* __restrict__ bp2,
                                                  float* __restrict__ out) {
    __shared__ float tr[128];
    int g = blockIdx.x;
    int f = threadIdx.x;
    float ic = invcnt[g];
    out[g * 128 + f] = sumD[g * 128 + f] * ic;
    tr[f] = sumT[g * 128 + f] * ic;
    __syncthreads();
    if (f < NCLS) {
        float acc = (ic > 0.f) ? bp2[f] : 0.f;
        for (int k = 0; k < 128; k++) acc = fmaf(tr[k], Wp2[k * NCLS + f], acc);
        out[NG * 128 + g * NCLS + f] = acc;
    }
}

// ---------------- launch ----------------

extern "C" void kernel_launch(void* const* d_in, const int* in_sizes, int n_in,
                              void* d_out, int out_size, void* d_ws, size_t ws_size,
                              hipStream_t stream) {
    const float* exp_f = (const float*)d_in[0];
    const float* cnv_f = (const float*)d_in[1];
    const int*   ei    = (const int*)d_in[2];
    const int*   batch = (const int*)d_in[3];
    const float* eps1e = (const float*)d_in[4];
    const float* W1e   = (const float*)d_in[5];
    const float* b1e   = (const float*)d_in[6];
    const float* eps2e = (const float*)d_in[7];
    const float* W2e   = (const float*)d_in[8];
    const float* b2e   = (const float*)d_in[9];
    const float* eps1c = (const float*)d_in[10];
    const float* W1c   = (const float*)d_in[11];
    const float* b1c   = (const float*)d_in[12];
    const float* eps2c = (const float*)d_in[13];
    const float* W2c   = (const float*)d_in[14];
    const float* b2c   = (const float*)d_in[15];
    const float* Wm    = (const float*)d_in[16];
    const float* bm    = (const float*)d_in[17];
    const float* Wp1   = (const float*)d_in[18];
    const float* bp1   = (const float*)d_in[19];
    const float* Wp2   = (const float*)d_in[20];
    const float* bp2   = (const float*)d_in[21];
    float* out = (float*)d_out;

    char* ws = (char*)d_ws;
    size_t off = 0;
    auto alloc = [&](size_t bytes) -> void* {
        void* p = ws + off;
        off = (off + bytes + 255) & ~(size_t)255;
        return p;
    };
    int* deg      = (int*)alloc((size_t)N_NODES * 4);
    int* rowptr   = (int*)alloc((size_t)(N_NODES + 1) * 4);
    int* cursor   = (int*)alloc((size_t)N_NODES * 4);
    int* csr      = (int*)alloc((size_t)N_EDGES * 4);
    int* gstart   = (int*)alloc((NG + 1) * 4);
    float* invcnt = (float*)alloc(NG * 4);
    int* blocksum = (int*)alloc(NB_SCAN * 4);
    int* blockoff = (int*)alloc(NB_SCAN * 4);
    float* sumD   = (float*)alloc((size_t)NG * 128 * 4);
    float* sumT   = (float*)alloc((size_t)NG * 128 * 4);

    unsigned short* Xe = (unsigned short*)alloc((size_t)N_PAD * 128 * 2);
    unsigned short* Xc = (unsigned short*)alloc((size_t)N_PAD * 64 * 2);
    unsigned short* E  = (unsigned short*)alloc((size_t)N_PAD * 64 * 2);
    unsigned short* A  = (unsigned short*)alloc((size_t)N_PAD * 128 * 2);
    unsigned short* B  = (unsigned short*)alloc((size_t)N_PAD * 128 * 2);
    unsigned short* C  = (unsigned short*)alloc((size_t)N_PAD * 128 * 2);
    unsigned short* D  = (unsigned short*)alloc((size_t)N_PAD * 128 * 2);
    unsigned short* T  = (unsigned short*)alloc((size_t)N_PAD * 128 * 2);

    unsigned short* WT1e = (unsigned short*)alloc(128 * 128 * 2);
    unsigned short* WT2e = (unsigned short*)alloc(128 * 128 * 2);
    unsigned short* WT1c = (unsigned short*)alloc(128 * 64 * 2);
    unsigned short* WT2c = (unsigned short*)alloc(128 * 128 * 2);
    unsigned short* WTm1 = (unsigned short*)alloc(128 * 128 * 2);
    unsigned short* WTm2 = (unsigned short*)alloc(128 * 128 * 2);
    unsigned short* WTp1 = (unsigned short*)alloc(128 * 128 * 2);

    const int* src = ei;
    const int* dst = ei + N_EDGES;

    hipMemsetAsync(deg, 0, (size_t)N_NODES * 4, stream);
    hipMemsetAsync(sumD, 0, (size_t)NG * 128 * 4 * 2, stream);  // sumD+sumT contiguous

    // CSR build + graph bounds (XCD-partitioned count/scatter)
    count_part_k<<<NCHUNK * EPART, 256, 0, stream>>>(dst, deg);
    gbounds_k<<<(N_NODES + 255) / 256, 256, 0, stream>>>(batch, gstart);
    scan_partial_k<<<NB_SCAN, 256, 0, stream>>>(deg, rowptr, blocksum);
    scan_root_k<<<1, 256, 0, stream>>>(blocksum, blockoff);
    scan_add_k<<<NB_SCAN, 256, 0, stream>>>(rowptr, cursor, blockoff);
    gfin_k<<<1, 64, 0, stream>>>(gstart, invcnt);
    scatter_part_k<<<NCHUNK * EPART, 256, 0, stream>>>(src, dst, cursor, csr);

    // conversions
    conv_bf_k<<<(N_NODES * 128 / 4 + 255) / 256, 256, 0, stream>>>(exp_f, Xe, N_NODES * 128 / 4);
    conv_bf_k<<<(N_NODES * 64 / 4 + 255) / 256, 256, 0, stream>>>(cnv_f, Xc, N_NODES * 64 / 4);
    wconv_all_k<<<416, 256, 0, stream>>>(W1e, W2e, W1c, W2c, Wm, Wp1,
                                         WT1e, WT2e, WT1c, WT2c, WTm1, WTm2, WTp1);

    const int AGG_GRID = (N_NODES * 64 + 255) / 256;
    const int AGG64_GRID = (N_NODES * 32 + 255) / 256;
    const int GEMM_GRID = (N_NODES + 31) / 32;  // 1563

    // exp branch
    agg128_bf_k<<<AGG_GRID, 256, 0, stream>>>((const uint32*)Xe, rowptr, csr, eps1e, (uint32*)A);
    gemm_bf_k<<<GEMM_GRID, 256, 0, stream>>>(A, WT1e, 128, nullptr, nullptr, 0, b1e, B, 1);
    agg128_bf_k<<<AGG_GRID, 256, 0, stream>>>((const uint32*)B, rowptr, csr, eps2e, (uint32*)A);
    gemm_bf_k<<<GEMM_GRID, 256, 0, stream>>>(A, WT2e, 128, nullptr, nullptr, 0, b2e, B, 1);
    // cnv branch
    agg64_bf_k<<<AGG64_GRID, 256, 0, stream>>>((const uint32*)Xc, rowptr, csr, eps1c, (uint32*)E);
    gemm_bf_k<<<GEMM_GRID, 256, 0, stream>>>(E, WT1c, 64, nullptr, nullptr, 0, b1c, C, 1);
    agg128_bf_k<<<AGG_GRID, 256, 0, stream>>>((const uint32*)C, rowptr, csr, eps2c, (uint32*)A);
    gemm_bf_k<<<GEMM_GRID, 256, 0, stream>>>(A, WT2c, 128, nullptr, nullptr, 0, b2c, C, 1);
    // mix: D = lrelu(B@Wm_top + C@Wm_bot + bm)
    gemm_bf_k<<<GEMM_GRID, 256, 0, stream>>>(B, WTm1, 128, C, WTm2, 128, bm, D, 1);
    // head pre-pool: T = relu(D@Wp1+bp1)
    gemm_bf_k<<<GEMM_GRID, 256, 0, stream>>>(D, WTp1, 128, nullptr, nullptr, 0, bp1, T, 2);
    // pooling + finalize (logits head applied post-pool)
    pool2_bf_k<<<(N_NODES + PCHUNK - 1) / PCHUNK, 64, 0, stream>>>((const uint32*)D, (const uint32*)T,
                                                                   batch, sumD, sumT);
    finalize_k<<<NG, 128, 0, stream>>>(sumD, sumT, invcnt, Wp2, bp2, out);
}

// Round 8
// 485.104 us; speedup vs baseline: 2.9343x; 1.0761x over previous
//
#include <hip/hip_runtime.h>

#define N_NODES 50000
#define N_PAD   50016          // padded rows so OOB tile loads stay in-buffer
#define N_EDGES 800000
#define HID 128
#define NCLS 10
#define NG 64
#define PWAVE 32               // nodes per wave in pooling
#define NB_SCAN ((N_NODES + 255) / 256)   // 196

// XCD-partitioned edge processing
#define EPART 8
#define PRANGE ((N_NODES + EPART - 1) / EPART)       // 6250 nodes per partition
#define ECHUNK 4096
#define NCHUNK ((N_EDGES + ECHUNK - 1) / ECHUNK)     // 196 chunks

typedef unsigned int uint32;
typedef __attribute__((ext_vector_type(8))) short bf16x8;
typedef __attribute__((ext_vector_type(4))) float f32x4;

// ---- bf16 helpers ----
__device__ __forceinline__ unsigned short f2bf(float f) {
    uint32 u = __float_as_uint(f);
    uint32 r = u + 0x7fffu + ((u >> 16) & 1u);   // RNE
    return (unsigned short)(r >> 16);
}
__device__ __forceinline__ float bflo(uint32 v) { return __uint_as_float(v << 16); }
__device__ __forceinline__ float bfhi(uint32 v) { return __uint_as_float(v & 0xffff0000u); }
__device__ __forceinline__ uint32 packbf(float a, float b) {
    return (uint32)f2bf(a) | ((uint32)f2bf(b) << 16);
}

// ---------------- CSR build (XCD-partitioned by dst range) ----------------

__global__ __launch_bounds__(256) void count_part_k(const int* __restrict__ dst,
                                                    int* __restrict__ deg) {
    int part = blockIdx.x & 7;
    int chunk = blockIdx.x >> 3;
    int lo = part * PRANGE;
    int hi = min(lo + PRANGE, N_NODES);
    int e0 = chunk * ECHUNK;
    int e1 = min(e0 + ECHUNK, N_EDGES);
    for (int i = e0 + threadIdx.x; i < e1; i += 256) {
        int d = dst[i];
        if (d >= lo && d < hi) atomicAdd(&deg[d], 1);
    }
}

__global__ __launch_bounds__(256) void scatter_part_k(const int* __restrict__ src,
                                                      const int* __restrict__ dst,
                                                      int* __restrict__ cursor,
                                                      int* __restrict__ csr) {
    int part = blockIdx.x & 7;
    int chunk = blockIdx.x >> 3;
    int lo = part * PRANGE;
    int hi = min(lo + PRANGE, N_NODES);
    int e0 = chunk * ECHUNK;
    int e1 = min(e0 + ECHUNK, N_EDGES);
    for (int i = e0 + threadIdx.x; i < e1; i += 256) {
        int d = dst[i];
        if (d >= lo && d < hi) {
            int pos = atomicAdd(&cursor[d], 1);
            csr[pos] = src[i];
        }
    }
}

__global__ void gbounds_k(const int* __restrict__ batch, int* __restrict__ gstart) {
    int i = blockIdx.x * blockDim.x + threadIdx.x;
    if (i >= N_NODES) return;
    int b = batch[i];
    int prev = (i == 0) ? -1 : batch[i - 1];
    for (int g = prev + 1; g <= b; g++) gstart[g] = i;
    if (i == N_NODES - 1) {
        for (int g = b + 1; g <= NG; g++) gstart[g] = N_NODES;
    }
}

__global__ void gfin_k(const int* __restrict__ gstart, float* __restrict__ invcnt) {
    int g = threadIdx.x;
    if (g < NG) {
        int c = gstart[g + 1] - gstart[g];
        invcnt[g] = (c > 0) ? 1.0f / (float)c : 0.0f;
    }
}

__device__ __forceinline__ int block_excl_scan_256(int v, int tid, int* total_out) {
    int lane = tid & 63, w = tid >> 6;
    int x = v;
#pragma unroll
    for (int off = 1; off < 64; off <<= 1) {
        int y = __shfl_up(x, off, 64);
        if (lane >= off) x += y;
    }
    __shared__ int wsum[4];
    if (lane == 63) wsum[w] = x;
    __syncthreads();
    int add = 0;
#pragma unroll
    for (int i = 0; i < 4; i++) add += (i < w) ? wsum[i] : 0;
    int total = wsum[0] + wsum[1] + wsum[2] + wsum[3];
    if (total_out) *total_out = total;
    return x - v + add;
}

__global__ __launch_bounds__(256) void scan_partial_k(const int* __restrict__ deg,
                                                      int* __restrict__ rowptr,
                                                      int* __restrict__ blocksum) {
    int tid = threadIdx.x;
    int gid = blockIdx.x * 256 + tid;
    int v = (gid < N_NODES) ? deg[gid] : 0;
    int total;
    int excl = block_excl_scan_256(v, tid, &total);
    if (gid < N_NODES) rowptr[gid] = excl;
    if (tid == 0) blocksum[blockIdx.x] = total;
}

__global__ __launch_bounds__(256) void scan_root_k(const int* __restrict__ blocksum,
                                                   int* __restrict__ blockoff) {
    int tid = threadIdx.x;
    int v = (tid < NB_SCAN) ? blocksum[tid] : 0;
    int excl = block_excl_scan_256(v, tid, nullptr);
    if (tid < NB_SCAN) blockoff[tid] = excl;
}

__global__ __launch_bounds__(256) void scan_add_k(int* __restrict__ rowptr,
                                                  int* __restrict__ cursor,
                                                  const int* __restrict__ blockoff) {
    int gid = blockIdx.x * 256 + threadIdx.x;
    if (gid < N_NODES) {
        int r = rowptr[gid] + blockoff[blockIdx.x];
        rowptr[gid] = r;
        cursor[gid] = r;
    }
    if (gid == 0) rowptr[N_NODES] = N_EDGES;
}

// ---------------- fp32 -> bf16 conversions ----------------

__global__ __launch_bounds__(256) void conv_bf_k(const float* __restrict__ in,
                                                 unsigned short* __restrict__ out, int n4) {
    int i = blockIdx.x * 256 + threadIdx.x;
    if (i >= n4) return;
    float4 v = *(const float4*)(in + (size_t)i * 4);
    uint32 lo = packbf(v.x, v.y);
    uint32 hi = packbf(v.z, v.w);
    uint2 o = {lo, hi};
    *(uint2*)(out + (size_t)i * 4) = o;
}

// Transpose+convert all weights. N=128 always. Block ranges hardcoded.
__global__ __launch_bounds__(256) void wconv_all_k(const float* W1e, const float* W2e,
                                                   const float* W1c, const float* W2c,
                                                   const float* Wm, const float* Wp1,
                                                   unsigned short* WT1e, unsigned short* WT2e,
                                                   unsigned short* WT1c, unsigned short* WT2c,
                                                   unsigned short* WTm1, unsigned short* WTm2,
                                                   unsigned short* WTp1) {
    int b = blockIdx.x;
    int t = threadIdx.x;
    const float* W; unsigned short* WT; int i; int K;
    if (b < 64)       { W = W1e; WT = WT1e; i = b * 256 + t;          K = 128; }
    else if (b < 128) { W = W2e; WT = WT2e; i = (b - 64) * 256 + t;   K = 128; }
    else if (b < 160) { W = W1c; WT = WT1c; i = (b - 128) * 256 + t;  K = 64;  }
    else if (b < 224) { W = W2c; WT = WT2c; i = (b - 160) * 256 + t;  K = 128; }
    else if (b < 352) { // Wm: 256x128, split into two K=128 halves
        i = (b - 224) * 256 + t;           // 0..32767
        int k = i >> 7, n = i & 127;
        unsigned short v = f2bf(Wm[i]);
        if (k < 128) WTm1[n * 128 + k] = v;
        else         WTm2[n * 128 + (k - 128)] = v;
        return;
    }
    else              { W = Wp1; WT = WTp1; i = (b - 352) * 256 + t;  K = 128; }
    int k = i >> 7, n = i & 127;   // i = k*128 + n
    if (k < K) WT[n * K + k] = f2bf(W[i]);
}

// ---------------- Aggregation (bf16): h[n] = (2+eps)*x[n] + sum x[src[e]] ----------------
// One wave per node; lane owns feature pair. Edge loop unrolled x8 for MLP
// (8 independent gathers in flight; round 5->6: 78.6 -> ~30 us).

__global__ __launch_bounds__(256) void agg128_bf_k(const uint32* __restrict__ X,
                                                   const int* __restrict__ rowptr,
                                                   const int* __restrict__ csr,
                                                   const float* __restrict__ eps,
                                                   uint32* __restrict__ H) {
    int wid = (blockIdx.x * 256 + threadIdx.x) >> 6;
    int lane = threadIdx.x & 63;
    if (wid >= N_NODES) return;
    float scale = 2.0f + eps[0];
    uint32 xv = X[(size_t)wid * 64 + lane];
    float a0 = scale * bflo(xv);
    float a1 = scale * bfhi(xv);
    int e = rowptr[wid], e1 = rowptr[wid + 1];
    for (; e + 8 <= e1; e += 8) {
        int i0 = csr[e],     i1 = csr[e + 1], i2 = csr[e + 2], i3 = csr[e + 3];
        int i4 = csr[e + 4], i5 = csr[e + 5], i6 = csr[e + 6], i7 = csr[e + 7];
        uint32 v0 = X[(size_t)i0 * 64 + lane];
        uint32 v1 = X[(size_t)i1 * 64 + lane];
        uint32 v2 = X[(size_t)i2 * 64 + lane];
        uint32 v3 = X[(size_t)i3 * 64 + lane];
        uint32 v4 = X[(size_t)i4 * 64 + lane];
        uint32 v5 = X[(size_t)i5 * 64 + lane];
        uint32 v6 = X[(size_t)i6 * 64 + lane];
        uint32 v7 = X[(size_t)i7 * 64 + lane];
        a0 += bflo(v0) + bflo(v1) + bflo(v2) + bflo(v3) +
              bflo(v4) + bflo(v5) + bflo(v6) + bflo(v7);
        a1 += bfhi(v0) + bfhi(v1) + bfhi(v2) + bfhi(v3) +
              bfhi(v4) + bfhi(v5) + bfhi(v6) + bfhi(v7);
    }
    if (e + 4 <= e1) {
        int i0 = csr[e], i1 = csr[e + 1], i2 = csr[e + 2], i3 = csr[e + 3];
        uint32 v0 = X[(size_t)i0 * 64 + lane];
        uint32 v1 = X[(size_t)i1 * 64 + lane];
        uint32 v2 = X[(size_t)i2 * 64 + lane];
        uint32 v3 = X[(size_t)i3 * 64 + lane];
        a0 += bflo(v0) + bflo(v1) + bflo(v2) + bflo(v3);
        a1 += bfhi(v0) + bfhi(v1) + bfhi(v2) + bfhi(v3);
        e += 4;
    }
    for (; e < e1; e++) {
        uint32 v = X[(size_t)csr[e] * 64 + lane];
        a0 += bflo(v);
        a1 += bfhi(v);
    }
    H[(size_t)wid * 64 + lane] = packbf(a0, a1);
}

// F=64: half-wave per node (32 lanes x u32 = 64 bf16). Same x8 unroll.
__global__ __launch_bounds__(256) void agg64_bf_k(const uint32* __restrict__ X,
                                                  const int* __restrict__ rowptr,
                                                  const int* __restrict__ csr,
                                                  const float* __restrict__ eps,
                                                  uint32* __restrict__ H) {
    int hw = (blockIdx.x * 256 + threadIdx.x) >> 5;
    int lane = threadIdx.x & 31;
    if (hw >= N_NODES) return;
    float scale = 2.0f + eps[0];
    uint32 xv = X[(size_t)hw * 32 + lane];
    float a0 = scale * bflo(xv);
    float a1 = scale * bfhi(xv);
    int e = rowptr[hw], e1 = rowptr[hw + 1];
    for (; e + 8 <= e1; e += 8) {
        int i0 = csr[e],     i1 = csr[e + 1], i2 = csr[e + 2], i3 = csr[e + 3];
        int i4 = csr[e + 4], i5 = csr[e + 5], i6 = csr[e + 6], i7 = csr[e + 7];
        uint32 v0 = X[(size_t)i0 * 32 + lane];
        uint32 v1 = X[(size_t)i1 * 32 + lane];
        uint32 v2 = X[(size_t)i2 * 32 + lane];
        uint32 v3 = X[(size_t)i3 * 32 + lane];
        uint32 v4 = X[(size_t)i4 * 32 + lane];
        uint32 v5 = X[(size_t)i5 * 32 + lane];
        uint32 v6 = X[(size_t)i6 * 32 + lane];
        uint32 v7 = X[(size_t)i7 * 32 + lane];
        a0 += bflo(v0) + bflo(v1) + bflo(v2) + bflo(v3) +
              bflo(v4) + bflo(v5) + bflo(v6) + bflo(v7);
        a1 += bfhi(v0) + bfhi(v1) + bfhi(v2) + bfhi(v3) +
              bfhi(v4) + bfhi(v5) + bfhi(v6) + bfhi(v7);
    }
    if (e + 4 <= e1) {
        int i0 = csr[e], i1 = csr[e + 1], i2 = csr[e + 2], i3 = csr[e + 3];
        uint32 v0 = X[(size_t)i0 * 32 + lane];
        uint32 v1 = X[(size_t)i1 * 32 + lane];
        uint32 v2 = X[(size_t)i2 * 32 + lane];
        uint32 v3 = X[(size_t)i3 * 32 + lane];
        a0 += bflo(v0) + bflo(v1) + bflo(v2) + bflo(v3);
        a1 += bfhi(v0) + bfhi(v1) + bfhi(v2) + bfhi(v3);
        e += 4;
    }
    for (; e < e1; e++) {
        uint32 v = X[(size_t)csr[e] * 32 + lane];
        a0 += bflo(v);
        a1 += bfhi(v);
    }
    H[(size_t)hw * 32 + lane] = packbf(a0, a1);
}

// ---------------- MFMA bf16 GEMM: out[M x 128] = act(A1@W1 (+ A2@W2) + bias) ----------------
// LDS-free; operands loaded with matching per-lane k-slot formula (permutation cancels).
// C/D mapping (m89/m91-verified): col = lane&15, row = (lane>>4)*4 + reg.

__global__ __launch_bounds__(256) void gemm_bf_k(const unsigned short* __restrict__ A1,
                                                 const unsigned short* __restrict__ WT1, int K1,
                                                 const unsigned short* __restrict__ A2,
                                                 const unsigned short* __restrict__ WT2, int K2,
                                                 const float* __restrict__ bias,
                                                 unsigned short* __restrict__ out, int act) {
    int tid = threadIdx.x;
    int w = tid >> 6, l = tid & 63;
    int row16 = blockIdx.x * 32 + (w & 1) * 16;
    int col16 = (w >> 1) * 64;
    int m = l & 15, g = l >> 4;

    f32x4 acc[4];
#pragma unroll
    for (int nt = 0; nt < 4; nt++) acc[nt] = (f32x4){0.f, 0.f, 0.f, 0.f};

    const unsigned short* A = A1;
    const unsigned short* WT = WT1;
    int K = K1;
    for (int pass = 0; pass < 2; ++pass) {
        if (pass) {
            if (A2 == nullptr) break;
            A = A2; WT = WT2; K = K2;
        }
        const unsigned short* ap = A + (size_t)(row16 + m) * K + g * 8;
        const unsigned short* bp = WT + (size_t)(col16 + m) * K + g * 8;
        for (int k0 = 0; k0 < K; k0 += 32) {
            bf16x8 af = *(const bf16x8*)(ap + k0);
#pragma unroll
            for (int nt = 0; nt < 4; nt++) {
                bf16x8 bfv = *(const bf16x8*)(bp + (size_t)nt * 16 * K + k0);
                acc[nt] = __builtin_amdgcn_mfma_f32_16x16x32_bf16(af, bfv, acc[nt], 0, 0, 0);
            }
        }
    }

#pragma unroll
    for (int nt = 0; nt < 4; nt++) {
        int col = col16 + nt * 16 + m;
        float bv = bias[col];
#pragma unroll
        for (int r = 0; r < 4; r++) {
            int row = row16 + g * 4 + r;
            if (row < N_NODES) {
                float v = acc[nt][r] + bv;
                if (act == 1) v = v > 0.f ? v : 0.2f * v;
                else if (act == 2) v = fmaxf(v, 0.f);
                out[(size_t)row * 128 + col] = f2bf(v);
            }
        }
    }
}

// ---------------- fused partial pooling over bf16 D and T ----------------
// One WAVE per 32 nodes (round 7: 391 waves @ 3.6% occupancy was latency-bound
// at 46 us). 1563 waves, node loop unrolled x4 -> 8 row-loads in flight.

__global__ __launch_bounds__(256) void pool2_bf_k(const uint32* __restrict__ D,
                                                  const uint32* __restrict__ T,
                                                  const int* __restrict__ batch,
                                                  float* __restrict__ sumD,
                                                  float* __restrict__ sumT) {
    int wv = (blockIdx.x * 256 + threadIdx.x) >> 6;   // global wave id
    int f = threadIdx.x & 63;                          // feature pair 0..63
    int i0 = wv * PWAVE;
    if (i0 >= N_NODES) return;
    int i1 = min(i0 + PWAVE, N_NODES);
    float d0 = 0.f, d1 = 0.f, t0 = 0.f, t1 = 0.f;
    int g = batch[i0];
    int i = i0;
    for (; i + 4 <= i1; i += 4) {
        int b0 = batch[i], b1 = batch[i + 1], b2 = batch[i + 2], b3 = batch[i + 3];
        uint32 dv0 = D[(size_t)i * 64 + f];
        uint32 dv1 = D[(size_t)(i + 1) * 64 + f];
        uint32 dv2 = D[(size_t)(i + 2) * 64 + f];
        uint32 dv3 = D[(size_t)(i + 3) * 64 + f];
        uint32 tv0 = T[(size_t)i * 64 + f];
        uint32 tv1 = T[(size_t)(i + 1) * 64 + f];
        uint32 tv2 = T[(size_t)(i + 2) * 64 + f];
        uint32 tv3 = T[(size_t)(i + 3) * 64 + f];
#define POOL_STEP(bg, dv, tv)                                          \
        if (bg != g) {                                                 \
            atomicAdd(&sumD[g * 128 + 2 * f], d0);                     \
            atomicAdd(&sumD[g * 128 + 2 * f + 1], d1);                 \
            atomicAdd(&sumT[g * 128 + 2 * f], t0);                     \
            atomicAdd(&sumT[g * 128 + 2 * f + 1], t1);                 \
            d0 = d1 = t0 = t1 = 0.f; g = bg;                           \
        }                                                              \
        d0 += bflo(dv); d1 += bfhi(dv);                                \
        t0 += bflo(tv); t1 += bfhi(tv);
        POOL_STEP(b0, dv0, tv0)
        POOL_STEP(b1, dv1, tv1)
        POOL_STEP(b2, dv2, tv2)
        POOL_STEP(b3, dv3, tv3)
    }
    for (; i < i1; i++) {
        int bg = batch[i];
        uint32 dv = D[(size_t)i * 64 + f];
        uint32 tv = T[(size_t)i * 64 + f];
        POOL_STEP(bg, dv, tv)
    }
#undef POOL_STEP
    atomicAdd(&sumD[g * 128 + 2 * f], d0);
    atomicAdd(&sumD[g * 128 + 2 * f + 1], d1);
    atomicAdd(&sumT[g * 128 + 2 * f], t0);
    atomicAdd(&sumT[g * 128 + 2 * f + 1], t1);
}

// ---------------- finalize ----------------

__global__ __launch_bounds__(128) void finalize_k(const float* __restrict__ sumD,
                                                  const float* __restrict__ sumT,
                                                  const float* __restrict__ invcnt,
                                                  const float* __restrict__ Wp2,
                                                  const float* __restrict__ bp2,
                                                  float* __restrict__ out) {
    __shared__ float tr[128];
    int g = blockIdx.x;
    int f = threadIdx.x;
    float ic = invcnt[g];
    out[g * 128 + f] = sumD[g * 128 + f] * ic;
    tr[f] = sumT[g * 128 + f] * ic;
    __syncthreads();
    if (f < NCLS) {
        float acc = (ic > 0.f) ? bp2[f] : 0.f;
        for (int k = 0; k < 128; k++) acc = fmaf(tr[k], Wp2[k * NCLS + f], acc);
        out[NG * 128 + g * NCLS + f] = acc;
    }
}

// ---------------- launch ----------------

extern "C" void kernel_launch(void* const* d_in, const int* in_sizes, int n_in,
                              void* d_out, int out_size, void* d_ws, size_t ws_size,
                              hipStream_t stream) {
    const float* exp_f = (const float*)d_in[0];
    const float* cnv_f = (const float*)d_in[1];
    const int*   ei    = (const int*)d_in[2];
    const int*   batch = (const int*)d_in[3];
    const float* eps1e = (const float*)d_in[4];
    const float* W1e   = (const float*)d_in[5];
    const float* b1e   = (const float*)d_in[6];
    const float* eps2e = (const float*)d_in[7];
    const float* W2e   = (const float*)d_in[8];
    const float* b2e   = (const float*)d_in[9];
    const float* eps1c = (const float*)d_in[10];
    const float* W1c   = (const float*)d_in[11];
    const float* b1c   = (const float*)d_in[12];
    const float* eps2c = (const float*)d_in[13];
    const float* W2c   = (const float*)d_in[14];
    const float* b2c   = (const float*)d_in[15];
    const float* Wm    = (const float*)d_in[16];
    const float* bm    = (const float*)d_in[17];
    const float* Wp1   = (const float*)d_in[18];
    const float* bp1   = (const float*)d_in[19];
    const float* Wp2   = (const float*)d_in[20];
    const float* bp2   = (const float*)d_in[21];
    float* out = (float*)d_out;

    char* ws = (char*)d_ws;
    size_t off = 0;
    auto alloc = [&](size_t bytes) -> void* {
        void* p = ws + off;
        off = (off + bytes + 255) & ~(size_t)255;
        return p;
    };
    int* deg      = (int*)alloc((size_t)N_NODES * 4);
    int* rowptr   = (int*)alloc((size_t)(N_NODES + 1) * 4);
    int* cursor   = (int*)alloc((size_t)N_NODES * 4);
    int* csr      = (int*)alloc((size_t)N_EDGES * 4);
    int* gstart   = (int*)alloc((NG + 1) * 4);
    float* invcnt = (float*)alloc(NG * 4);
    int* blocksum = (int*)alloc(NB_SCAN * 4);
    int* blockoff = (int*)alloc(NB_SCAN * 4);
    float* sumD   = (float*)alloc((size_t)NG * 128 * 4);
    float* sumT   = (float*)alloc((size_t)NG * 128 * 4);

    unsigned short* Xe = (unsigned short*)alloc((size_t)N_PAD * 128 * 2);
    unsigned short* Xc = (unsigned short*)alloc((size_t)N_PAD * 64 * 2);
    unsigned short* E  = (unsigned short*)alloc((size_t)N_PAD * 64 * 2);
    unsigned short* A  = (unsigned short*)alloc((size_t)N_PAD * 128 * 2);
    unsigned short* B  = (unsigned short*)alloc((size_t)N_PAD * 128 * 2);
    unsigned short* C  = (unsigned short*)alloc((size_t)N_PAD * 128 * 2);
    unsigned short* D  = (unsigned short*)alloc((size_t)N_PAD * 128 * 2);
    unsigned short* T  = (unsigned short*)alloc((size_t)N_PAD * 128 * 2);

    unsigned short* WT1e = (unsigned short*)alloc(128 * 128 * 2);
    unsigned short* WT2e = (unsigned short*)alloc(128 * 128 * 2);
    unsigned short* WT1c = (unsigned short*)alloc(128 * 64 * 2);
    unsigned short* WT2c = (unsigned short*)alloc(128 * 128 * 2);
    unsigned short* WTm1 = (unsigned short*)alloc(128 * 128 * 2);
    unsigned short* WTm2 = (unsigned short*)alloc(128 * 128 * 2);
    unsigned short* WTp1 = (unsigned short*)alloc(128 * 128 * 2);

    const int* src = ei;
    const int* dst = ei + N_EDGES;

    hipMemsetAsync(deg, 0, (size_t)N_NODES * 4, stream);
    hipMemsetAsync(sumD, 0, (size_t)NG * 128 * 4 * 2, stream);  // sumD+sumT contiguous

    // CSR build + graph bounds (XCD-partitioned count/scatter)
    count_part_k<<<NCHUNK * EPART, 256, 0, stream>>>(dst, deg);
    gbounds_k<<<(N_NODES + 255) / 256, 256, 0, stream>>>(batch, gstart);
    scan_partial_k<<<NB_SCAN, 256, 0, stream>>>(deg, rowptr, blocksum);
    scan_root_k<<<1, 256, 0, stream>>>(blocksum, blockoff);
    scan_add_k<<<NB_SCAN, 256, 0, stream>>>(rowptr, cursor, blockoff);
    gfin_k<<<1, 64, 0, stream>>>(gstart, invcnt);
    scatter_part_k<<<NCHUNK * EPART, 256, 0, stream>>>(src, dst, cursor, csr);

    // conversions
    conv_bf_k<<<(N_NODES * 128 / 4 + 255) / 256, 256, 0, stream>>>(exp_f, Xe, N_NODES * 128 / 4);
    conv_bf_k<<<(N_NODES * 64 / 4 + 255) / 256, 256, 0, stream>>>(cnv_f, Xc, N_NODES * 64 / 4);
    wconv_all_k<<<416, 256, 0, stream>>>(W1e, W2e, W1c, W2c, Wm, Wp1,
                                         WT1e, WT2e, WT1c, WT2c, WTm1, WTm2, WTp1);

    const int AGG_GRID = (N_NODES * 64 + 255) / 256;
    const int AGG64_GRID = (N_NODES * 32 + 255) / 256;
    const int GEMM_GRID = (N_NODES + 31) / 32;  // 1563
    const int POOL_GRID = ((N_NODES + PWAVE - 1) / PWAVE * 64 + 255) / 256;  // 391

    // exp branch
    agg128_bf_k<<<AGG_GRID, 256, 0, stream>>>((const uint32*)Xe, rowptr, csr, eps1e, (uint32*)A);
    gemm_bf_k<<<GEMM_GRID, 256, 0, stream>>>(A, WT1e, 128, nullptr, nullptr, 0, b1e, B, 1);
    agg128_bf_k<<<AGG_GRID, 256, 0, stream>>>((const uint32*)B, rowptr, csr, eps2e, (uint32*)A);
    gemm_bf_k<<<GEMM_GRID, 256, 0, stream>>>(A, WT2e, 128, nullptr, nullptr, 0, b2e, B, 1);
    // cnv branch
    agg64_bf_k<<<AGG64_GRID, 256, 0, stream>>>((const uint32*)Xc, rowptr, csr, eps1c, (uint32*)E);
    gemm_bf_k<<<GEMM_GRID, 256, 0, stream>>>(E, WT1c, 64, nullptr, nullptr, 0, b1c, C, 1);
    agg128_bf_k<<<AGG_GRID, 256, 0, stream>>>((const uint32*)C, rowptr, csr, eps2c, (uint32*)A);
    gemm_bf_k<<<GEMM_GRID, 256, 0, stream>>>(A, WT2c, 128, nullptr, nullptr, 0, b2c, C, 1);
    // mix: D = lrelu(B@Wm_top + C@Wm_bot + bm)
    gemm_bf_k<<<GEMM_GRID, 256, 0, stream>>>(B, WTm1, 128, C, WTm2, 128, bm, D, 1);
    // head pre-pool: T = relu(D@Wp1+bp1)
    gemm_bf_k<<<GEMM_GRID, 256, 0, stream>>>(D, WTp1, 128, nullptr, nullptr, 0, bp1, T, 2);
    // pooling + finalize (logits head applied post-pool)
    pool2_bf_k<<<POOL_GRID, 256, 0, stream>>>((const uint32*)D, (const uint32*)T,
                                              batch, sumD, sumT);
    finalize_k<<<NG, 128, 0, stream>>>(sumD, sumT, invcnt, Wp2, bp2, out);
}

// Round 9
// 452.407 us; speedup vs baseline: 3.1463x; 1.0723x over previous
//
#include <hip/hip_runtime.h>

#define N_NODES 50000
#define N_PAD   50016
#define N_EDGES 800000
#define HID 128
#define NCLS 10
#define NG 64
#define PWAVE 32
#define NB_SCAN ((N_NODES + 255) / 256)   // 196

// XCD-partitioned edge processing
#define EPART 8
#define PRANGE ((N_NODES + EPART - 1) / EPART)
#define ECHUNK 4096
#define NCHUNK ((N_EDGES + ECHUNK - 1) / ECHUNK)

typedef unsigned int uint32;
typedef __attribute__((ext_vector_type(8))) short bf16x8;
typedef __attribute__((ext_vector_type(4))) float f32x4;

__device__ __forceinline__ unsigned short f2bf(float f) {
    uint32 u = __float_as_uint(f);
    uint32 r = u + 0x7fffu + ((u >> 16) & 1u);   // RNE
    return (unsigned short)(r >> 16);
}
__device__ __forceinline__ float bflo(uint32 v) { return __uint_as_float(v << 16); }
__device__ __forceinline__ float bfhi(uint32 v) { return __uint_as_float(v & 0xffff0000u); }
__device__ __forceinline__ uint32 packbf(float a, float b) {
    return (uint32)f2bf(a) | ((uint32)f2bf(b) << 16);
}

// ---------------- CSR build (XCD-partitioned by dst range) ----------------

__global__ __launch_bounds__(256) void count_part_k(const int* __restrict__ dst,
                                                    int* __restrict__ deg) {
    int part = blockIdx.x & 7;
    int chunk = blockIdx.x >> 3;
    int lo = part * PRANGE;
    int hi = min(lo + PRANGE, N_NODES);
    int e0 = chunk * ECHUNK;
    int e1 = min(e0 + ECHUNK, N_EDGES);
    for (int i = e0 + threadIdx.x; i < e1; i += 256) {
        int d = dst[i];
        if (d >= lo && d < hi) atomicAdd(&deg[d], 1);
    }
}

__global__ __launch_bounds__(256) void scatter_part_k(const int* __restrict__ src,
                                                      const int* __restrict__ dst,
                                                      int* __restrict__ cursor,
                                                      int* __restrict__ csr) {
    int part = blockIdx.x & 7;
    int chunk = blockIdx.x >> 3;
    int lo = part * PRANGE;
    int hi = min(lo + PRANGE, N_NODES);
    int e0 = chunk * ECHUNK;
    int e1 = min(e0 + ECHUNK, N_EDGES);
    for (int i = e0 + threadIdx.x; i < e1; i += 256) {
        int d = dst[i];
        if (d >= lo && d < hi) {
            int pos = atomicAdd(&cursor[d], 1);
            csr[pos] = src[i];
        }
    }
}

__global__ void gbounds_k(const int* __restrict__ batch, int* __restrict__ gstart) {
    int i = blockIdx.x * blockDim.x + threadIdx.x;
    if (i >= N_NODES) return;
    int b = batch[i];
    int prev = (i == 0) ? -1 : batch[i - 1];
    for (int g = prev + 1; g <= b; g++) gstart[g] = i;
    if (i == N_NODES - 1) {
        for (int g = b + 1; g <= NG; g++) gstart[g] = N_NODES;
    }
}

__device__ __forceinline__ int block_excl_scan_256(int v, int tid, int* total_out) {
    int lane = tid & 63, w = tid >> 6;
    int x = v;
#pragma unroll
    for (int off = 1; off < 64; off <<= 1) {
        int y = __shfl_up(x, off, 64);
        if (lane >= off) x += y;
    }
    __shared__ int wsum[4];
    if (lane == 63) wsum[w] = x;
    __syncthreads();
    int add = 0;
#pragma unroll
    for (int i = 0; i < 4; i++) add += (i < w) ? wsum[i] : 0;
    int total = wsum[0] + wsum[1] + wsum[2] + wsum[3];
    if (total_out) *total_out = total;
    return x - v + add;
}

__global__ __launch_bounds__(256) void scan_partial_k(const int* __restrict__ deg,
                                                      int* __restrict__ rowptr,
                                                      int* __restrict__ blocksum) {
    int tid = threadIdx.x;
    int gid = blockIdx.x * 256 + tid;
    int v = (gid < N_NODES) ? deg[gid] : 0;
    int total;
    int excl = block_excl_scan_256(v, tid, &total);
    if (gid < N_NODES) rowptr[gid] = excl;
    if (tid == 0) blocksum[blockIdx.x] = total;
}

// scan of block sums + graph invcnt (folded gfin; gbounds ran earlier)
__global__ __launch_bounds__(256) void scan_root_k(const int* __restrict__ blocksum,
                                                   int* __restrict__ blockoff,
                                                   const int* __restrict__ gstart,
                                                   float* __restrict__ invcnt) {
    int tid = threadIdx.x;
    int v = (tid < NB_SCAN) ? blocksum[tid] : 0;
    int excl = block_excl_scan_256(v, tid, nullptr);
    if (tid < NB_SCAN) blockoff[tid] = excl;
    if (tid < NG) {
        int c = gstart[tid + 1] - gstart[tid];
        invcnt[tid] = (c > 0) ? 1.0f / (float)c : 0.0f;
    }
}

__global__ __launch_bounds__(256) void scan_add_k(int* __restrict__ rowptr,
                                                  int* __restrict__ cursor,
                                                  const int* __restrict__ blockoff) {
    int gid = blockIdx.x * 256 + threadIdx.x;
    if (gid < N_NODES) {
        int r = rowptr[gid] + blockoff[blockIdx.x];
        rowptr[gid] = r;
        cursor[gid] = r;
    }
    if (gid == 0) rowptr[N_NODES] = N_EDGES;
}

// ---------------- fp32 -> bf16 conversions (both inputs, one launch) ----------------

__global__ __launch_bounds__(256) void conv_both_k(const float* __restrict__ inE,
                                                   unsigned short* __restrict__ outE, int n4e,
                                                   const float* __restrict__ inC,
                                                   unsigned short* __restrict__ outC, int n4c) {
    int i = blockIdx.x * 256 + threadIdx.x;
    const float* in;
    unsigned short* out;
    if (i < n4e) { in = inE; out = outE; }
    else { i -= n4e; if (i >= n4c) return; in = inC; out = outC; }
    float4 v = *(const float4*)(in + (size_t)i * 4);
    uint2 o = {packbf(v.x, v.y), packbf(v.z, v.w)};
    *(uint2*)(out + (size_t)i * 4) = o;
}

__global__ __launch_bounds__(256) void wconv_all_k(const float* W1e, const float* W2e,
                                                   const float* W1c, const float* W2c,
                                                   const float* Wm, const float* Wp1,
                                                   unsigned short* WT1e, unsigned short* WT2e,
                                                   unsigned short* WT1c, unsigned short* WT2c,
                                                   unsigned short* WTm1, unsigned short* WTm2,
                                                   unsigned short* WTp1) {
    int b = blockIdx.x;
    int t = threadIdx.x;
    const float* W; unsigned short* WT; int i; int K;
    if (b < 64)       { W = W1e; WT = WT1e; i = b * 256 + t;          K = 128; }
    else if (b < 128) { W = W2e; WT = WT2e; i = (b - 64) * 256 + t;   K = 128; }
    else if (b < 160) { W = W1c; WT = WT1c; i = (b - 128) * 256 + t;  K = 64;  }
    else if (b < 224) { W = W2c; WT = WT2c; i = (b - 160) * 256 + t;  K = 128; }
    else if (b < 352) {
        i = (b - 224) * 256 + t;
        int k = i >> 7, n = i & 127;
        unsigned short v = f2bf(Wm[i]);
        if (k < 128) WTm1[n * 128 + k] = v;
        else         WTm2[n * 128 + (k - 128)] = v;
        return;
    }
    else              { W = Wp1; WT = WTp1; i = (b - 352) * 256 + t;  K = 128; }
    int k = i >> 7, n = i & 127;
    if (k < K) WT[n * K + k] = f2bf(W[i]);
}

// ---------------- shared agg-row helper (128 features, lane owns pair) ----------------

__device__ __forceinline__ uint32 agg_row128(const uint32* __restrict__ X,
                                             const int* __restrict__ rowptr,
                                             const int* __restrict__ csr,
                                             int n, int lane, float scale) {
    uint32 xv = X[(size_t)n * 64 + lane];
    float a0 = scale * bflo(xv);
    float a1 = scale * bfhi(xv);
    int e = rowptr[n], e1 = rowptr[n + 1];
    for (; e + 8 <= e1; e += 8) {
        int i0 = csr[e],     i1 = csr[e + 1], i2 = csr[e + 2], i3 = csr[e + 3];
        int i4 = csr[e + 4], i5 = csr[e + 5], i6 = csr[e + 6], i7 = csr[e + 7];
        uint32 v0 = X[(size_t)i0 * 64 + lane];
        uint32 v1 = X[(size_t)i1 * 64 + lane];
        uint32 v2 = X[(size_t)i2 * 64 + lane];
        uint32 v3 = X[(size_t)i3 * 64 + lane];
        uint32 v4 = X[(size_t)i4 * 64 + lane];
        uint32 v5 = X[(size_t)i5 * 64 + lane];
        uint32 v6 = X[(size_t)i6 * 64 + lane];
        uint32 v7 = X[(size_t)i7 * 64 + lane];
        a0 += bflo(v0) + bflo(v1) + bflo(v2) + bflo(v3) +
              bflo(v4) + bflo(v5) + bflo(v6) + bflo(v7);
        a1 += bfhi(v0) + bfhi(v1) + bfhi(v2) + bfhi(v3) +
              bfhi(v4) + bfhi(v5) + bfhi(v6) + bfhi(v7);
    }
    if (e + 4 <= e1) {
        int i0 = csr[e], i1 = csr[e + 1], i2 = csr[e + 2], i3 = csr[e + 3];
        uint32 v0 = X[(size_t)i0 * 64 + lane];
        uint32 v1 = X[(size_t)i1 * 64 + lane];
        uint32 v2 = X[(size_t)i2 * 64 + lane];
        uint32 v3 = X[(size_t)i3 * 64 + lane];
        a0 += bflo(v0) + bflo(v1) + bflo(v2) + bflo(v3);
        a1 += bfhi(v0) + bfhi(v1) + bfhi(v2) + bfhi(v3);
        e += 4;
    }
    for (; e < e1; e++) {
        uint32 v = X[(size_t)csr[e] * 64 + lane];
        a0 += bflo(v);
        a1 += bfhi(v);
    }
    return packbf(a0, a1);
}

// ---------------- FUSED GIN layer (K=128): out = lrelu(agg(X) @ W + b) ----------------
// Block = 256 thr = 4 waves = 32 output rows. Phase 1: wave w aggregates nodes
// base+w*8..+8 into an XOR-swizzled LDS tile (byte ^= (row&7)<<4 -- row stride
// 256B is same-bank 16-way otherwise, G4). Phase 2: MFMA, A-frags from LDS,
// B-frags from L2-resident WT with the SAME per-lane k-slot formula.
// Two independent problem sets in one launch (grid split at nblk1).

__global__ __launch_bounds__(256) void agg_gemm_k(const uint32* __restrict__ X1,
                                                  const float* __restrict__ eps1,
                                                  const unsigned short* __restrict__ WT1p,
                                                  const float* __restrict__ b1,
                                                  unsigned short* __restrict__ out1,
                                                  const uint32* __restrict__ X2,
                                                  const float* __restrict__ eps2,
                                                  const unsigned short* __restrict__ WT2p,
                                                  const float* __restrict__ b2,
                                                  unsigned short* __restrict__ out2,
                                                  const int* __restrict__ rowptr,
                                                  const int* __restrict__ csr,
                                                  int nblk1) {
    __shared__ uint32 lds[32 * 64];   // 32 rows x 128 bf16, swizzled
    int blk = blockIdx.x;
    const uint32* X; const float* epsp; const unsigned short* WT;
    const float* bias; unsigned short* out;
    if (blk < nblk1) { X = X1; epsp = eps1; WT = WT1p; bias = b1; out = out1; }
    else { blk -= nblk1; X = X2; epsp = eps2; WT = WT2p; bias = b2; out = out2; }

    int tid = threadIdx.x;
    int w = tid >> 6, lane = tid & 63;
    int base = blk * 32;
    float scale = 2.0f + epsp[0];

    // phase 1: aggregate 8 rows per wave into LDS
    for (int s = 0; s < 8; s++) {
        int lrow = w * 8 + s;
        int n = base + lrow;
        uint32 outv = 0;
        if (n < N_NODES) outv = agg_row128(X, rowptr, csr, n, lane, scale);
        int byte = (lrow * 256 + lane * 4) ^ ((lrow & 7) << 4);
        lds[byte >> 2] = outv;
    }
    __syncthreads();

    // phase 2: 16x16x32 MFMA tile (rows base+(w&1)*16, cols (w>>1)*64)
    int m = lane & 15, g = lane >> 4;
    int lrow = (w & 1) * 16 + m;
    int row16 = base + (w & 1) * 16;
    int col16 = (w >> 1) * 64;

    f32x4 acc[4];
#pragma unroll
    for (int nt = 0; nt < 4; nt++) acc[nt] = (f32x4){0.f, 0.f, 0.f, 0.f};

    const unsigned short* bp = WT + (size_t)(col16 + m) * 128 + g * 8;
#pragma unroll
    for (int k0 = 0; k0 < 128; k0 += 32) {
        int ab = (lrow * 256 + (g * 8 + k0) * 2) ^ ((lrow & 7) << 4);
        bf16x8 af = *(const bf16x8*)((const char*)lds + ab);
#pragma unroll
        for (int nt = 0; nt < 4; nt++) {
            bf16x8 bfv = *(const bf16x8*)(bp + (size_t)nt * 16 * 128 + k0);
            acc[nt] = __builtin_amdgcn_mfma_f32_16x16x32_bf16(af, bfv, acc[nt], 0, 0, 0);
        }
    }

#pragma unroll
    for (int nt = 0; nt < 4; nt++) {
        int col = col16 + nt * 16 + m;
        float bv = bias[col];
#pragma unroll
        for (int r = 0; r < 4; r++) {
            int row = row16 + g * 4 + r;
            if (row < N_NODES) {
                float v = acc[nt][r] + bv;
                v = v > 0.f ? v : 0.2f * v;   // lrelu (all GIN layers)
                out[(size_t)row * 128 + col] = f2bf(v);
            }
        }
    }
}

// ---------------- agg64 (cnv layer 1 input, K=64) ----------------

__global__ __launch_bounds__(256) void agg64_bf_k(const uint32* __restrict__ X,
                                                  const int* __restrict__ rowptr,
                                                  const int* __restrict__ csr,
                                                  const float* __restrict__ eps,
                                                  uint32* __restrict__ H) {
    int hw = (blockIdx.x * 256 + threadIdx.x) >> 5;
    int lane = threadIdx.x & 31;
    if (hw >= N_NODES) return;
    float scale = 2.0f + eps[0];
    uint32 xv = X[(size_t)hw * 32 + lane];
    float a0 = scale * bflo(xv);
    float a1 = scale * bfhi(xv);
    int e = rowptr[hw], e1 = rowptr[hw + 1];
    for (; e + 8 <= e1; e += 8) {
        int i0 = csr[e],     i1 = csr[e + 1], i2 = csr[e + 2], i3 = csr[e + 3];
        int i4 = csr[e + 4], i5 = csr[e + 5], i6 = csr[e + 6], i7 = csr[e + 7];
        uint32 v0 = X[(size_t)i0 * 32 + lane];
        uint32 v1 = X[(size_t)i1 * 32 + lane];
        uint32 v2 = X[(size_t)i2 * 32 + lane];
        uint32 v3 = X[(size_t)i3 * 32 + lane];
        uint32 v4 = X[(size_t)i4 * 32 + lane];
        uint32 v5 = X[(size_t)i5 * 32 + lane];
        uint32 v6 = X[(size_t)i6 * 32 + lane];
        uint32 v7 = X[(size_t)i7 * 32 + lane];
        a0 += bflo(v0) + bflo(v1) + bflo(v2) + bflo(v3) +
              bflo(v4) + bflo(v5) + bflo(v6) + bflo(v7);
        a1 += bfhi(v0) + bfhi(v1) + bfhi(v2) + bfhi(v3) +
              bfhi(v4) + bfhi(v5) + bfhi(v6) + bfhi(v7);
    }
    if (e + 4 <= e1) {
        int i0 = csr[e], i1 = csr[e + 1], i2 = csr[e + 2], i3 = csr[e + 3];
        uint32 v0 = X[(size_t)i0 * 32 + lane];
        uint32 v1 = X[(size_t)i1 * 32 + lane];
        uint32 v2 = X[(size_t)i2 * 32 + lane];
        uint32 v3 = X[(size_t)i3 * 32 + lane];
        a0 += bflo(v0) + bflo(v1) + bflo(v2) + bflo(v3);
        a1 += bfhi(v0) + bfhi(v1) + bfhi(v2) + bfhi(v3);
        e += 4;
    }
    for (; e < e1; e++) {
        uint32 v = X[(size_t)csr[e] * 32 + lane];
        a0 += bflo(v);
        a1 += bfhi(v);
    }
    H[(size_t)hw * 32 + lane] = packbf(a0, a1);
}

// ---------------- MFMA bf16 GEMM (A from global) ----------------

__global__ __launch_bounds__(256) void gemm_bf_k(const unsigned short* __restrict__ A1,
                                                 const unsigned short* __restrict__ WT1, int K1,
                                                 const unsigned short* __restrict__ A2,
                                                 const unsigned short* __restrict__ WT2, int K2,
                                                 const float* __restrict__ bias,
                                                 unsigned short* __restrict__ out, int act) {
    int tid = threadIdx.x;
    int w = tid >> 6, l = tid & 63;
    int row16 = blockIdx.x * 32 + (w & 1) * 16;
    int col16 = (w >> 1) * 64;
    int m = l & 15, g = l >> 4;

    f32x4 acc[4];
#pragma unroll
    for (int nt = 0; nt < 4; nt++) acc[nt] = (f32x4){0.f, 0.f, 0.f, 0.f};

    const unsigned short* A = A1;
    const unsigned short* WT = WT1;
    int K = K1;
    for (int pass = 0; pass < 2; ++pass) {
        if (pass) {
            if (A2 == nullptr) break;
            A = A2; WT = WT2; K = K2;
        }
        const unsigned short* ap = A + (size_t)(row16 + m) * K + g * 8;
        const unsigned short* bp = WT + (size_t)(col16 + m) * K + g * 8;
        for (int k0 = 0; k0 < K; k0 += 32) {
            bf16x8 af = *(const bf16x8*)(ap + k0);
#pragma unroll
            for (int nt = 0; nt < 4; nt++) {
                bf16x8 bfv = *(const bf16x8*)(bp + (size_t)nt * 16 * K + k0);
                acc[nt] = __builtin_amdgcn_mfma_f32_16x16x32_bf16(af, bfv, acc[nt], 0, 0, 0);
            }
        }
    }

#pragma unroll
    for (int nt = 0; nt < 4; nt++) {
        int col = col16 + nt * 16 + m;
        float bv = bias[col];
#pragma unroll
        for (int r = 0; r < 4; r++) {
            int row = row16 + g * 4 + r;
            if (row < N_NODES) {
                float v = acc[nt][r] + bv;
                if (act == 1) v = v > 0.f ? v : 0.2f * v;
                else if (act == 2) v = fmaxf(v, 0.f);
                out[(size_t)row * 128 + col] = f2bf(v);
            }
        }
    }
}

// ---------------- fused partial pooling over bf16 D and T ----------------

__global__ __launch_bounds__(256) void pool2_bf_k(const uint32* __restrict__ D,
                                                  const uint32* __restrict__ T,
                                                  const int* __restrict__ batch,
                                                  float* __restrict__ sumD,
                                                  float* __restrict__ sumT) {
    int wv = (blockIdx.x * 256 + threadIdx.x) >> 6;
    int f = threadIdx.x & 63;
    int i0 = wv * PWAVE;
    if (i0 >= N_NODES) return;
    int i1 = min(i0 + PWAVE, N_NODES);
    float d0 = 0.f, d1 = 0.f, t0 = 0.f, t1 = 0.f;
    int g = batch[i0];
    int i = i0;
    for (; i + 4 <= i1; i += 4) {
        int b0 = batch[i], b1 = batch[i + 1], b2 = batch[i + 2], b3 = batch[i + 3];
        uint32 dv0 = D[(size_t)i * 64 + f];
        uint32 dv1 = D[(size_t)(i + 1) * 64 + f];
        uint32 dv2 = D[(size_t)(i + 2) * 64 + f];
        uint32 dv3 = D[(size_t)(i + 3) * 64 + f];
        uint32 tv0 = T[(size_t)i * 64 + f];
        uint32 tv1 = T[(size_t)(i + 1) * 64 + f];
        uint32 tv2 = T[(size_t)(i + 2) * 64 + f];
        uint32 tv3 = T[(size_t)(i + 3) * 64 + f];
#define POOL_STEP(bg, dv, tv)                                          \
        if (bg != g) {                                                 \
            atomicAdd(&sumD[g * 128 + 2 * f], d0);                     \
            atomicAdd(&sumD[g * 128 + 2 * f + 1], d1);                 \
            atomicAdd(&sumT[g * 128 + 2 * f], t0);                     \
            atomicAdd(&sumT[g * 128 + 2 * f + 1], t1);                 \
            d0 = d1 = t0 = t1 = 0.f; g = bg;                           \
        }                                                              \
        d0 += bflo(dv); d1 += bfhi(dv);                                \
        t0 += bflo(tv); t1 += bfhi(tv);
        POOL_STEP(b0, dv0, tv0)
        POOL_STEP(b1, dv1, tv1)
        POOL_STEP(b2, dv2, tv2)
        POOL_STEP(b3, dv3, tv3)
    }
    for (; i < i1; i++) {
        int bg = batch[i];
        uint32 dv = D[(size_t)i * 64 + f];
        uint32 tv = T[(size_t)i * 64 + f];
        POOL_STEP(bg, dv, tv)
    }
#undef POOL_STEP
    atomicAdd(&sumD[g * 128 + 2 * f], d0);
    atomicAdd(&sumD[g * 128 + 2 * f + 1], d1);
    atomicAdd(&sumT[g * 128 + 2 * f], t0);
    atomicAdd(&sumT[g * 128 + 2 * f + 1], t1);
}

// ---------------- finalize ----------------

__global__ __launch_bounds__(128) void finalize_k(const float* __restrict__ sumD,
                                                  const float* __restrict__ sumT,
                                                  const float* __restrict__ invcnt,
                                                  const float* __restrict__ Wp2,
                                                  const float* __restrict__ bp2,
                                                  float* __restrict__ out) {
    __shared__ float tr[128];
    int g = blockIdx.x;
    int f = threadIdx.x;
    float ic = invcnt[g];
    out[g * 128 + f] = sumD[g * 128 + f] * ic;
    tr[f] = sumT[g * 128 + f] * ic;
    __syncthreads();
    if (f < NCLS) {
        float acc = (ic > 0.f) ? bp2[f] : 0.f;
        for (int k = 0; k < 128; k++) acc = fmaf(tr[k], Wp2[k * NCLS + f], acc);
        out[NG * 128 + g * NCLS + f] = acc;
    }
}

// ---------------- launch ----------------

extern "C" void kernel_launch(void* const* d_in, const int* in_sizes, int n_in,
                              void* d_out, int out_size, void* d_ws, size_t ws_size,
                              hipStream_t stream) {
    const float* exp_f = (const float*)d_in[0];
    const float* cnv_f = (const float*)d_in[1];
    const int*   ei    = (const int*)d_in[2];
    const int*   batch = (const int*)d_in[3];
    const float* eps1e = (const float*)d_in[4];
    const float* W1e   = (const float*)d_in[5];
    const float* b1e   = (const float*)d_in[6];
    const float* eps2e = (const float*)d_in[7];
    const float* W2e   = (const float*)d_in[8];
    const float* b2e   = (const float*)d_in[9];
    const float* eps1c = (const float*)d_in[10];
    const float* W1c   = (const float*)d_in[11];
    const float* b1c   = (const float*)d_in[12];
    const float* eps2c = (const float*)d_in[13];
    const float* W2c   = (const float*)d_in[14];
    const float* b2c   = (const float*)d_in[15];
    const float* Wm    = (const float*)d_in[16];
    const float* bm    = (const float*)d_in[17];
    const float* Wp1   = (const float*)d_in[18];
    const float* bp1   = (const float*)d_in[19];
    const float* Wp2   = (const float*)d_in[20];
    const float* bp2   = (const float*)d_in[21];
    float* out = (float*)d_out;

    char* ws = (char*)d_ws;
    size_t off = 0;
    auto alloc = [&](size_t bytes) -> void* {
        void* p = ws + off;
        off = (off + bytes + 255) & ~(size_t)255;
        return p;
    };
    int* deg      = (int*)alloc((size_t)N_NODES * 4);
    int* rowptr   = (int*)alloc((size_t)(N_NODES + 1) * 4);
    int* cursor   = (int*)alloc((size_t)N_NODES * 4);
    int* csr      = (int*)alloc((size_t)N_EDGES * 4);
    int* gstart   = (int*)alloc((NG + 1) * 4);
    float* invcnt = (float*)alloc(NG * 4);
    int* blocksum = (int*)alloc(NB_SCAN * 4);
    int* blockoff = (int*)alloc(NB_SCAN * 4);
    float* sumD   = (float*)alloc((size_t)NG * 128 * 4);
    float* sumT   = (float*)alloc((size_t)NG * 128 * 4);

    unsigned short* Xe = (unsigned short*)alloc((size_t)N_PAD * 128 * 2);
    unsigned short* Xc = (unsigned short*)alloc((size_t)N_PAD * 64 * 2);
    unsigned short* E  = (unsigned short*)alloc((size_t)N_PAD * 64 * 2);
    unsigned short* B  = (unsigned short*)alloc((size_t)N_PAD * 128 * 2);
    unsigned short* C  = (unsigned short*)alloc((size_t)N_PAD * 128 * 2);
    unsigned short* B2 = (unsigned short*)alloc((size_t)N_PAD * 128 * 2);
    unsigned short* C2 = (unsigned short*)alloc((size_t)N_PAD * 128 * 2);
    unsigned short* D  = (unsigned short*)alloc((size_t)N_PAD * 128 * 2);
    unsigned short* T  = (unsigned short*)alloc((size_t)N_PAD * 128 * 2);

    unsigned short* WT1e = (unsigned short*)alloc(128 * 128 * 2);
    unsigned short* WT2e = (unsigned short*)alloc(128 * 128 * 2);
    unsigned short* WT1c = (unsigned short*)alloc(128 * 64 * 2);
    unsigned short* WT2c = (unsigned short*)alloc(128 * 128 * 2);
    unsigned short* WTm1 = (unsigned short*)alloc(128 * 128 * 2);
    unsigned short* WTm2 = (unsigned short*)alloc(128 * 128 * 2);
    unsigned short* WTp1 = (unsigned short*)alloc(128 * 128 * 2);

    const int* src = ei;
    const int* dst = ei + N_EDGES;

    hipMemsetAsync(deg, 0, (size_t)N_NODES * 4, stream);
    hipMemsetAsync(sumD, 0, (size_t)NG * 128 * 4 * 2, stream);  // sumD+sumT contiguous

    // CSR build + graph bounds
    count_part_k<<<NCHUNK * EPART, 256, 0, stream>>>(dst, deg);
    gbounds_k<<<(N_NODES + 255) / 256, 256, 0, stream>>>(batch, gstart);
    scan_partial_k<<<NB_SCAN, 256, 0, stream>>>(deg, rowptr, blocksum);
    scan_root_k<<<1, 256, 0, stream>>>(blocksum, blockoff, gstart, invcnt);
    scan_add_k<<<NB_SCAN, 256, 0, stream>>>(rowptr, cursor, blockoff);
    scatter_part_k<<<NCHUNK * EPART, 256, 0, stream>>>(src, dst, cursor, csr);

    // conversions
    const int n4e = N_NODES * 128 / 4, n4c = N_NODES * 64 / 4;
    conv_both_k<<<(n4e + n4c + 255) / 256, 256, 0, stream>>>(exp_f, Xe, n4e, cnv_f, Xc, n4c);
    wconv_all_k<<<416, 256, 0, stream>>>(W1e, W2e, W1c, W2c, Wm, Wp1,
                                         WT1e, WT2e, WT1c, WT2c, WTm1, WTm2, WTp1);

    const int AGG64_GRID = (N_NODES * 32 + 255) / 256;
    const int GEMM_GRID = (N_NODES + 31) / 32;  // 1563

    // layer 1: exp fused; cnv agg64 + gemm (K=64 path not fused)
    agg_gemm_k<<<GEMM_GRID, 256, 0, stream>>>((const uint32*)Xe, eps1e, WT1e, b1e, B,
                                              nullptr, nullptr, nullptr, nullptr, nullptr,
                                              rowptr, csr, GEMM_GRID);
    agg64_bf_k<<<AGG64_GRID, 256, 0, stream>>>((const uint32*)Xc, rowptr, csr, eps1c, (uint32*)E);
    gemm_bf_k<<<GEMM_GRID, 256, 0, stream>>>(E, WT1c, 64, nullptr, nullptr, 0, b1c, C, 1);
    // layer 2: exp + cnv fused, ONE launch (grid split)
    agg_gemm_k<<<2 * GEMM_GRID, 256, 0, stream>>>((const uint32*)B, eps2e, WT2e, b2e, B2,
                                                  (const uint32*)C, eps2c, WT2c, b2c, C2,
                                                  rowptr, csr, GEMM_GRID);
    // mix: D = lrelu(B2@Wm_top + C2@Wm_bot + bm)
    gemm_bf_k<<<GEMM_GRID, 256, 0, stream>>>(B2, WTm1, 128, C2, WTm2, 128, bm, D, 1);
    // head pre-pool: T = relu(D@Wp1+bp1)
    gemm_bf_k<<<GEMM_GRID, 256, 0, stream>>>(D, WTp1, 128, nullptr, nullptr, 0, bp1, T, 2);
    // pooling + finalize
    const int POOL_GRID = ((N_NODES + PWAVE - 1) / PWAVE * 64 + 255) / 256;
    pool2_bf_k<<<POOL_GRID, 256, 0, stream>>>((const uint32*)D, (const uint32*)T,
                                              batch, sumD, sumT);
    finalize_k<<<NG, 128, 0, stream>>>(sumD, sumT, invcnt, Wp2, bp2, out);
}